// Round 2
// baseline (9270.920 us; speedup 1.0000x reference)
//
#include <hip/hip_runtime.h>
#include <hip/hip_fp16.h>
#include <math.h>

#define NHEADS 8
#define NG 64

__device__ __forceinline__ float elu_f(float x)   { return x > 0.f ? x : expf(x) - 1.f; }
__device__ __forceinline__ float lrelu_f(float x) { return x >= 0.f ? x : 0.2f * x; }

// ---- typed 4-wide load/store + scalar converts (fp32 / fp16) ----
__device__ __forceinline__ float4 ld4(const float* p) { return *(const float4*)p; }
__device__ __forceinline__ float4 ld4(const __half* p) {
    const __half2* q = (const __half2*)p;
    __half2 a = q[0], b = q[1];
    return make_float4(__half2float(a.x), __half2float(a.y),
                       __half2float(b.x), __half2float(b.y));
}
__device__ __forceinline__ void st4(float* p, float4 v) { *(float4*)p = v; }
__device__ __forceinline__ void st4(__half* p, float4 v) {
    __half2 a, b;
    a.x = __float2half(v.x); a.y = __float2half(v.y);
    b.x = __float2half(v.z); b.y = __float2half(v.w);
    __half2* q = (__half2*)p; q[0] = a; q[1] = b;
}
__device__ __forceinline__ float scl(float v)  { return v; }
__device__ __forceinline__ float scl(__half v) { return __half2float(v); }
__device__ __forceinline__ void sst(float* p, float v)  { *p = v; }
__device__ __forceinline__ void sst(__half* p, float v) { *p = __float2half(v); }

// ---------------- CSR build (by dst) ----------------
__global__ void hist_kernel(const int* __restrict__ ei, int E, int Etot, int* __restrict__ counts) {
    int e = blockIdx.x * blockDim.x + threadIdx.x;
    if (e >= Etot) return;
    int dst = (e < E) ? ei[E + e] : (e - E);   // self-loop for e >= E
    atomicAdd(&counts[dst], 1);
}

__global__ void scan_kernel(const int* __restrict__ counts, int* __restrict__ offsets,
                            int* __restrict__ cursor, int N) {
    __shared__ int sdata[256];
    __shared__ int carry_s;
    if (threadIdx.x == 0) carry_s = 0;
    __syncthreads();
    for (int base = 0; base < N; base += 256) {
        int i = base + (int)threadIdx.x;
        int v = (i < N) ? counts[i] : 0;
        sdata[threadIdx.x] = v;
        __syncthreads();
        for (int off = 1; off < 256; off <<= 1) {
            int t = (threadIdx.x >= (unsigned)off) ? sdata[threadIdx.x - off] : 0;
            __syncthreads();
            sdata[threadIdx.x] += t;
            __syncthreads();
        }
        int excl = sdata[threadIdx.x] - v + carry_s;
        if (i < N) { offsets[i] = excl; cursor[i] = excl; }
        __syncthreads();
        if (threadIdx.x == 255) carry_s += sdata[255];
        __syncthreads();
    }
    if (threadIdx.x == 0) offsets[N] = carry_s;
}

__global__ void scatter_kernel(const int* __restrict__ ei, int E, int Etot,
                               int* __restrict__ cursor, int* __restrict__ perm_src) {
    int e = blockIdx.x * blockDim.x + threadIdx.x;
    if (e >= Etot) return;
    int src, dst;
    if (e < E) { src = ei[e]; dst = ei[E + e]; }
    else       { src = e - E; dst = e - E; }
    int pos = atomicAdd(&cursor[dst], 1);
    perm_src[pos] = src;
}

// ---------------- tiled GEMM: C[M,N] = A[M,K] @ B[K,N] ----------------
// 64x64 tile, BK=16, 256 threads, 4x4 per thread. N,K multiples of 16/64; M guarded.
template <typename TA, typename TC>
__global__ __launch_bounds__(256) void gemm_kernel(const TA* __restrict__ A,
                                                   const float* __restrict__ B,
                                                   TC* __restrict__ C,
                                                   int M, int N, int K) {
    __shared__ float As[16][64];
    __shared__ float Bs[16][64];
    const int tid  = threadIdx.x;
    const int row0 = blockIdx.y * 64, col0 = blockIdx.x * 64;
    const int am = tid >> 2, ak = (tid & 3) << 2;
    const int bk = tid >> 4, bn = (tid & 15) << 2;
    const int ty = (tid >> 4) << 2, tx = (tid & 15) << 2;
    float acc[4][4] = {};
    const int arow = row0 + am;
    for (int k0 = 0; k0 < K; k0 += 16) {
        float4 a4 = make_float4(0.f, 0.f, 0.f, 0.f);
        if (arow < M) a4 = ld4(A + (size_t)arow * K + k0 + ak);
        As[ak + 0][am] = a4.x; As[ak + 1][am] = a4.y;
        As[ak + 2][am] = a4.z; As[ak + 3][am] = a4.w;
        *(float4*)&Bs[bk][bn] = *(const float4*)(B + (size_t)(k0 + bk) * N + col0 + bn);
        __syncthreads();
#pragma unroll
        for (int k = 0; k < 16; ++k) {
            float4 ar = *(const float4*)&As[k][ty];
            float4 br = *(const float4*)&Bs[k][tx];
            acc[0][0] += ar.x * br.x; acc[0][1] += ar.x * br.y; acc[0][2] += ar.x * br.z; acc[0][3] += ar.x * br.w;
            acc[1][0] += ar.y * br.x; acc[1][1] += ar.y * br.y; acc[1][2] += ar.y * br.z; acc[1][3] += ar.y * br.w;
            acc[2][0] += ar.z * br.x; acc[2][1] += ar.z * br.y; acc[2][2] += ar.z * br.z; acc[2][3] += ar.z * br.w;
            acc[3][0] += ar.w * br.x; acc[3][1] += ar.w * br.y; acc[3][2] += ar.w * br.z; acc[3][3] += ar.w * br.w;
        }
        __syncthreads();
    }
#pragma unroll
    for (int i = 0; i < 4; ++i) {
        int r = row0 + ty + i;
        if (r < M) {
            float4 o = make_float4(acc[i][0], acc[i][1], acc[i][2], acc[i][3]);
            st4(C + (size_t)r * N + col0 + tx, o);
        }
    }
}

// ---------------- per-(node,head) attention logits ----------------
template <typename TH>
__global__ void al_kernel(const TH* __restrict__ ht, const float* __restrict__ a_src,
                          const float* __restrict__ a_dst, float* __restrict__ al_s,
                          float* __restrict__ al_d, int N, int C) {
    int wid  = (int)((blockIdx.x * blockDim.x + threadIdx.x) >> 6);
    int lane = threadIdx.x & 63;
    if (wid >= N * NHEADS) return;
    int n = wid / NHEADS, h = wid % NHEADS;
    const TH* hp = ht + (size_t)n * (NHEADS * C) + h * C;
    float ss = 0.f, sd = 0.f;
    for (int c = lane; c < C; c += 64) {
        float v = scl(hp[c]);
        ss += v * a_src[h * C + c];
        sd += v * a_dst[h * C + c];
    }
#pragma unroll
    for (int off = 32; off > 0; off >>= 1) {
        ss += __shfl_down(ss, off);
        sd += __shfl_down(sd, off);
    }
    if (lane == 0) { al_s[wid] = ss; al_d[wid] = sd; }
}

// ---------------- segment softmax (per dst node, per head) ----------------
__global__ void alpha_kernel(const int* __restrict__ offsets, const int* __restrict__ perm_src,
                             const float* __restrict__ al_s, const float* __restrict__ al_d,
                             float* __restrict__ alpha, int N) {
    int idx = blockIdx.x * blockDim.x + threadIdx.x;
    if (idx >= N * NHEADS) return;
    int n = idx / NHEADS, h = idx % NHEADS;
    int s = offsets[n], e = offsets[n + 1];
    float ad = al_d[idx];
    float m = -1e30f;
    for (int p = s; p < e; ++p) {
        float v = lrelu_f(al_s[perm_src[p] * NHEADS + h] + ad);
        m = fmaxf(m, v);
    }
    float denom = 0.f;
    for (int p = s; p < e; ++p) {
        float v  = lrelu_f(al_s[perm_src[p] * NHEADS + h] + ad);
        float ex = expf(v - m);
        alpha[(size_t)p * NHEADS + h] = ex;
        denom += ex;
    }
    float inv = 1.f / (denom + 1e-16f);
    for (int p = s; p < e; ++p) alpha[(size_t)p * NHEADS + h] *= inv;
}

// ---------------- alpha-weighted aggregation + epilogue ----------------
// MODE 0: out[n, 0:HC] = elu(acc + bias)         (concat layers)
// MODE 1: out[n, 0:C]  = elu(mean_h acc + bias)  (final layer)
template <int HC, int C, int MODE, typename TH, typename TO>
__global__ __launch_bounds__(256) void agg_kernel(const TH* __restrict__ ht,
                                                  const float* __restrict__ alpha,
                                                  const int* __restrict__ offsets,
                                                  const int* __restrict__ perm_src,
                                                  const float* __restrict__ bias,
                                                  TO* __restrict__ out, int N) {
    constexpr int PER = HC / 256;
    int n = blockIdx.x;
    int tid = threadIdx.x;
    float acc[PER];
#pragma unroll
    for (int i = 0; i < PER; ++i) acc[i] = 0.f;
    int s = offsets[n], e = offsets[n + 1];
    for (int p = s; p < e; ++p) {
        int src = perm_src[p];
        const TH* hp = ht + (size_t)src * HC;
#pragma unroll
        for (int i = 0; i < PER; ++i) {
            int j = tid + i * 256;
            float a = alpha[(size_t)p * NHEADS + (j / C)];
            acc[i] += a * scl(hp[j]);
        }
    }
    if (MODE == 0) {
#pragma unroll
        for (int i = 0; i < PER; ++i) {
            int j = tid + i * 256;
            sst(&out[(size_t)n * HC + j], elu_f(acc[i] + bias[j]));
        }
    } else {
        float srow = 0.f;
#pragma unroll
        for (int i = 0; i < PER; ++i) srow += acc[i];
        sst(&out[(size_t)n * C + tid], elu_f(srow * (1.f / NHEADS) + bias[tid]));
    }
}

// ---------------- pooling ----------------
__global__ void gstart_kernel(const int* __restrict__ batch, int* __restrict__ gstart, int N) {
    int n = blockIdx.x * blockDim.x + threadIdx.x;
    if (n > N) return;
    if (n == 0) {
        int b0 = batch[0];
        for (int g = 0; g <= b0; ++g) gstart[g] = 0;
    } else if (n == N) {
        int bl = batch[N - 1];
        for (int g = bl + 1; g <= NG; ++g) gstart[g] = N;
    } else {
        int bp = batch[n - 1], bc = batch[n];
        for (int g = bp + 1; g <= bc; ++g) gstart[g] = n;
    }
}

__global__ void pool_kernel(const float* __restrict__ h5, const int* __restrict__ gstart,
                            float* __restrict__ pooled) {
    int g = blockIdx.x, c = threadIdx.x;  // 256 threads
    int s = gstart[g], e = gstart[g + 1];
    float sum = 0.f;
    for (int n = s; n < e; ++n) sum += h5[(size_t)n * 256 + c];
    float cnt = fmaxf((float)(e - s), 1.f);
    pooled[g * 256 + c] = elu_f(sum / cnt);
}

__global__ void linear_kernel(const float* __restrict__ pooled, const float* __restrict__ W,
                              const float* __restrict__ b, float* __restrict__ out) {
    int g = blockIdx.x, c = threadIdx.x;  // 128 threads
    float s = b[c];
    for (int k = 0; k < 256; ++k) s += pooled[g * 256 + k] * W[k * 128 + c];
    out[g * 128 + c] = s;
}

// ---------------- 5-layer pipeline (typed) ----------------
template <typename TIO, typename TH>
static void run_pipeline(const float* x, const float* const* W, const float* const* asrc,
                         const float* const* adst, const float* const* bias,
                         char* rawIO, char* rawHT,
                         float* al_s, float* al_d, float* alpha_buf,
                         const int* offsets, const int* perm_src,
                         int N, hipStream_t stream) {
    TIO* bufIO = (TIO*)rawIO;
    TH*  bufHT = (TH*)rawHT;
    // layer 0: x[N,128] @ W0[128,512]
    {
        dim3 g(512 / 64, (N + 63) / 64);
        gemm_kernel<float, TH><<<g, 256, 0, stream>>>(x, W[0], bufHT, N, 512, 128);
        al_kernel<TH><<<(N * NHEADS * 64 + 255) / 256, 256, 0, stream>>>(bufHT, asrc[0], adst[0], al_s, al_d, N, 64);
        alpha_kernel<<<(N * NHEADS + 255) / 256, 256, 0, stream>>>(offsets, perm_src, al_s, al_d, alpha_buf, N);
        agg_kernel<512, 64, 0, TH, TIO><<<N, 256, 0, stream>>>(bufHT, alpha_buf, offsets, perm_src, bias[0], bufIO, N);
    }
    int Kdim = 512;
    for (int l = 1; l < 5; ++l) {
        dim3 g(2048 / 64, (N + 63) / 64);
        gemm_kernel<TIO, TH><<<g, 256, 0, stream>>>(bufIO, W[l], bufHT, N, 2048, Kdim);
        al_kernel<TH><<<(N * NHEADS * 64 + 255) / 256, 256, 0, stream>>>(bufHT, asrc[l], adst[l], al_s, al_d, N, 256);
        alpha_kernel<<<(N * NHEADS + 255) / 256, 256, 0, stream>>>(offsets, perm_src, al_s, al_d, alpha_buf, N);
        if (l < 4)
            agg_kernel<2048, 256, 0, TH, TIO><<<N, 256, 0, stream>>>(bufHT, alpha_buf, offsets, perm_src, bias[l], bufIO, N);
        else
            agg_kernel<2048, 256, 1, TH, float><<<N, 256, 0, stream>>>(bufHT, alpha_buf, offsets, perm_src, bias[l], (float*)rawIO, N);
        Kdim = 2048;
    }
}

// ---------------- host ----------------
extern "C" void kernel_launch(void* const* d_in, const int* in_sizes, int n_in,
                              void* d_out, int out_size, void* d_ws, size_t ws_size,
                              hipStream_t stream) {
    const float* x     = (const float*)d_in[0];
    const int*   ei    = (const int*)d_in[1];
    const int*   batch = (const int*)d_in[2];
    const float* W[5]    = {(const float*)d_in[3],  (const float*)d_in[7],  (const float*)d_in[11],
                            (const float*)d_in[15], (const float*)d_in[19]};
    const float* asrc[5] = {(const float*)d_in[4],  (const float*)d_in[8],  (const float*)d_in[12],
                            (const float*)d_in[16], (const float*)d_in[20]};
    const float* adst[5] = {(const float*)d_in[5],  (const float*)d_in[9],  (const float*)d_in[13],
                            (const float*)d_in[17], (const float*)d_in[21]};
    const float* bias[5] = {(const float*)d_in[6],  (const float*)d_in[10], (const float*)d_in[14],
                            (const float*)d_in[18], (const float*)d_in[22]};
    const float* Wlin = (const float*)d_in[23];
    const float* blin = (const float*)d_in[24];

    const int N    = in_sizes[0] / 128;
    const int E    = in_sizes[1] / 2;
    const int Etot = E + N;

    auto align256 = [](size_t b) { return (b + 255) & ~(size_t)255; };

    // misc region sizes
    size_t sz_counts = align256((size_t)N * 4);
    size_t sz_off    = align256((size_t)(N + 1) * 4);
    size_t sz_cur    = align256((size_t)N * 4);
    size_t sz_perm   = align256((size_t)Etot * 4);
    size_t sz_al     = align256((size_t)N * NHEADS * 4);
    size_t sz_alpha  = align256((size_t)Etot * NHEADS * 4);
    size_t sz_gst    = align256((size_t)(NG + 1) * 4);
    size_t sz_pool   = align256((size_t)NG * 256 * 4);
    size_t misc = sz_counts + sz_off + sz_cur + sz_perm + 2 * sz_al + sz_alpha + sz_gst + sz_pool;

    size_t bigf = align256((size_t)N * 2048 * sizeof(float));
    size_t bigh = align256((size_t)N * 2048 * sizeof(__half));

    int path;
    if      (ws_size >= misc + 2 * bigf)        path = 0;  // fp32 IO, fp32 ht
    else if (ws_size >= misc + bigf + bigh)     path = 1;  // fp32 IO, fp16 ht
    else if (ws_size >= misc + 2 * bigh)        path = 2;  // fp16 IO, fp16 ht
    else {
        // workspace too small for any path: fail cleanly (no OOB write)
        hipMemsetAsync(d_out, 0, (size_t)out_size * sizeof(float), stream);
        return;
    }

    char* ws = (char*)d_ws;
    size_t off = 0;
    auto carve = [&](size_t bytes) { void* p = ws + off; off += bytes; return p; };
    int*   counts   = (int*)carve(sz_counts);
    int*   offsets  = (int*)carve(sz_off);
    int*   cursor   = (int*)carve(sz_cur);
    int*   perm_src = (int*)carve(sz_perm);
    float* al_s     = (float*)carve(sz_al);
    float* al_d     = (float*)carve(sz_al);
    float* alpha    = (float*)carve(sz_alpha);
    int*   gstart   = (int*)carve(sz_gst);
    float* pooled   = (float*)carve(sz_pool);
    char*  rawIO    = (char*)carve(path == 2 ? bigh : bigf);
    char*  rawHT    = (char*)carve(path == 0 ? bigf : bigh);

    // CSR build
    hipMemsetAsync(counts, 0, (size_t)N * 4, stream);
    hist_kernel<<<(Etot + 255) / 256, 256, 0, stream>>>(ei, E, Etot, counts);
    scan_kernel<<<1, 256, 0, stream>>>(counts, offsets, cursor, N);
    scatter_kernel<<<(Etot + 255) / 256, 256, 0, stream>>>(ei, E, Etot, cursor, perm_src);

    if (path == 0)
        run_pipeline<float, float>(x, W, asrc, adst, bias, rawIO, rawHT, al_s, al_d, alpha, offsets, perm_src, N, stream);
    else if (path == 1)
        run_pipeline<float, __half>(x, W, asrc, adst, bias, rawIO, rawHT, al_s, al_d, alpha, offsets, perm_src, N, stream);
    else
        run_pipeline<__half, __half>(x, W, asrc, adst, bias, rawIO, rawHT, al_s, al_d, alpha, offsets, perm_src, N, stream);

    gstart_kernel<<<(N + 1 + 255) / 256, 256, 0, stream>>>(batch, gstart, N);
    pool_kernel<<<NG, 256, 0, stream>>>((const float*)rawIO, gstart, pooled);
    linear_kernel<<<NG, 128, 0, stream>>>(pooled, Wlin, blin, (float*)d_out);
}

// Round 3
// 1476.385 us; speedup vs baseline: 6.2795x; 6.2795x over previous
//
#include <hip/hip_runtime.h>
#include <hip/hip_fp16.h>
#include <math.h>

#define NHEADS 8
#define NG 64

typedef _Float16 half8_t __attribute__((ext_vector_type(8)));
typedef float    float4_t __attribute__((ext_vector_type(4)));
typedef __attribute__((address_space(1))) const void g_void;
typedef __attribute__((address_space(3))) void l_void;

__device__ __forceinline__ float elu_f(float x)   { return x > 0.f ? x : expf(x) - 1.f; }
__device__ __forceinline__ float lrelu_f(float x) { return x >= 0.f ? x : 0.2f * x; }

// ---- typed 4-wide load/store + scalar converts (fp32 / fp16) ----
__device__ __forceinline__ float4 ld4(const float* p) { return *(const float4*)p; }
__device__ __forceinline__ float4 ld4(const __half* p) {
    const __half2* q = (const __half2*)p;
    __half2 a = q[0], b = q[1];
    return make_float4(__half2float(a.x), __half2float(a.y),
                       __half2float(b.x), __half2float(b.y));
}
__device__ __forceinline__ void st4(float* p, float4 v) { *(float4*)p = v; }
__device__ __forceinline__ void st4(__half* p, float4 v) {
    __half2 a, b;
    a.x = __float2half(v.x); a.y = __float2half(v.y);
    b.x = __float2half(v.z); b.y = __float2half(v.w);
    __half2* q = (__half2*)p; q[0] = a; q[1] = b;
}
__device__ __forceinline__ float scl(float v)  { return v; }
__device__ __forceinline__ float scl(__half v) { return __half2float(v); }
__device__ __forceinline__ void sst(float* p, float v)  { *p = v; }
__device__ __forceinline__ void sst(__half* p, float v) { *p = __float2half(v); }

// ---------------- CSR build (by dst) ----------------
__global__ void hist_kernel(const int* __restrict__ ei, int E, int Etot, int* __restrict__ counts) {
    int e = blockIdx.x * blockDim.x + threadIdx.x;
    if (e >= Etot) return;
    int dst = (e < E) ? ei[E + e] : (e - E);   // self-loop for e >= E
    atomicAdd(&counts[dst], 1);
}

__global__ void scan_kernel(const int* __restrict__ counts, int* __restrict__ offsets,
                            int* __restrict__ cursor, int N) {
    __shared__ int sdata[256];
    __shared__ int carry_s;
    if (threadIdx.x == 0) carry_s = 0;
    __syncthreads();
    for (int base = 0; base < N; base += 256) {
        int i = base + (int)threadIdx.x;
        int v = (i < N) ? counts[i] : 0;
        sdata[threadIdx.x] = v;
        __syncthreads();
        for (int off = 1; off < 256; off <<= 1) {
            int t = (threadIdx.x >= (unsigned)off) ? sdata[threadIdx.x - off] : 0;
            __syncthreads();
            sdata[threadIdx.x] += t;
            __syncthreads();
        }
        int excl = sdata[threadIdx.x] - v + carry_s;
        if (i < N) { offsets[i] = excl; cursor[i] = excl; }
        __syncthreads();
        if (threadIdx.x == 255) carry_s += sdata[255];
        __syncthreads();
    }
    if (threadIdx.x == 0) offsets[N] = carry_s;
}

__global__ void scatter_kernel(const int* __restrict__ ei, int E, int Etot,
                               int* __restrict__ cursor, int* __restrict__ perm_src) {
    int e = blockIdx.x * blockDim.x + threadIdx.x;
    if (e >= Etot) return;
    int src, dst;
    if (e < E) { src = ei[e]; dst = ei[E + e]; }
    else       { src = e - E; dst = e - E; }
    int pos = atomicAdd(&cursor[dst], 1);
    perm_src[pos] = src;
}

// ---------------- W[K][N] fp32 -> Wt[N][K] fp16 (tiled transpose) ----------------
__global__ __launch_bounds__(256) void transpose_conv_kernel(const float* __restrict__ W,
                                                             __half* __restrict__ Wt,
                                                             int K, int N) {
    __shared__ float t[32][33];
    int nb = blockIdx.x * 32, kb = blockIdx.y * 32;
    int tx = threadIdx.x & 31, ty = threadIdx.x >> 5;  // ty 0..7
#pragma unroll
    for (int r = 0; r < 32; r += 8)
        t[ty + r][tx] = W[(size_t)(kb + ty + r) * N + nb + tx];
    __syncthreads();
#pragma unroll
    for (int r = 0; r < 32; r += 8)
        Wt[(size_t)(nb + ty + r) * K + kb + tx] = __float2half(t[tx][ty + r]);
}

// ---------------- fp32 -> fp16 convert ----------------
struct h4s { __half a, b, c, d; };
__global__ void f32_to_f16_kernel(const float* __restrict__ in, __half* __restrict__ out, long n4) {
    long i = (long)blockIdx.x * blockDim.x + threadIdx.x;
    if (i >= n4) return;
    float4 v = ((const float4*)in)[i];
    h4s o; o.a = __float2half(v.x); o.b = __float2half(v.y);
    o.c = __float2half(v.z); o.d = __float2half(v.w);
    ((h4s*)out)[i] = o;
}

// ---------------- MFMA GEMM: C[M][N] = A[M][K] @ Bt[N][K]^T, all fp16 in, fp16 out ----
// 128x128 tile, BK=64, 4 waves (2x2 of 64x64), global_load_lds staging with
// XOR-swizzled global source + linear LDS dest; swizzled ds_read_b128 fragment reads.
__global__ __launch_bounds__(256) void gemm_mfma_kernel(const __half* __restrict__ A,
                                                        const __half* __restrict__ Bt,
                                                        __half* __restrict__ C,
                                                        int M, int N, int K) {
    __shared__ __align__(16) __half Asm[128 * 64];
    __shared__ __align__(16) __half Bsm[128 * 64];
    const int tid  = threadIdx.x;
    const int lane = tid & 63;
    const int wave = tid >> 6;
    const int row0 = blockIdx.y * 128;
    const int col0 = blockIdx.x * 128;

    const int l15 = lane & 15;
    const int l4  = lane >> 4;            // 0..3
    const int wm  = (wave >> 1) * 64;     // wave's m offset in tile
    const int wn  = (wave & 1) * 64;      // wave's n offset in tile

    // staging: wave w, issue i covers tile rows (i*4+w)*8 .. +8 (8 rows x 128B = 1KB)
    // lane l: row-in-group = l>>3, physical 16B chunk = l&7,
    // logical k-chunk = (l&7) ^ (row&7) with row&7 = l>>3  (XOR involution)
    const int sl_row = lane >> 3;              // 0..7
    const int sl_kch = (lane & 7) ^ sl_row;    // logical k-chunk to fetch

    float4_t acc[4][4];
#pragma unroll
    for (int i = 0; i < 4; ++i)
#pragma unroll
        for (int j = 0; j < 4; ++j)
            acc[i][j] = (float4_t){0.f, 0.f, 0.f, 0.f};

    for (int k0 = 0; k0 < K; k0 += 64) {
#pragma unroll
        for (int i = 0; i < 4; ++i) {
            int rr = (i * 4 + wave) * 8 + sl_row;     // 0..127
            int ar = row0 + rr; if (ar >= M) ar = M - 1;   // clamp (values unused)
            const __half* ga = A + (size_t)ar * K + k0 + sl_kch * 8;
            char* la = (char*)Asm + ((i * 4 + wave) * 1024 + lane * 16);
            __builtin_amdgcn_global_load_lds((g_void*)ga, (l_void*)la, 16, 0, 0);
            const __half* gb = Bt + (size_t)(col0 + rr) * K + k0 + sl_kch * 8;
            char* lb = (char*)Bsm + ((i * 4 + wave) * 1024 + lane * 16);
            __builtin_amdgcn_global_load_lds((g_void*)gb, (l_void*)lb, 16, 0, 0);
        }
        __syncthreads();   // drains vmcnt before barrier (compiler-inserted)
#pragma unroll
        for (int kh = 0; kh < 2; ++kh) {
            half8_t af[4], bf[4];
#pragma unroll
            for (int f = 0; f < 4; ++f) {
                int rowa = wm + f * 16 + l15;
                int ca = (kh * 4 + l4) ^ (rowa & 7);
                af[f] = *(const half8_t*)((const char*)Asm + rowa * 128 + ca * 16);
                int rowb = wn + f * 16 + l15;
                int cb = (kh * 4 + l4) ^ (rowb & 7);
                bf[f] = *(const half8_t*)((const char*)Bsm + rowb * 128 + cb * 16);
            }
#pragma unroll
            for (int fm = 0; fm < 4; ++fm)
#pragma unroll
                for (int fn = 0; fn < 4; ++fn)
                    acc[fm][fn] = __builtin_amdgcn_mfma_f32_16x16x32_f16(af[fm], bf[fn], acc[fm][fn], 0, 0, 0);
        }
        __syncthreads();
    }

    // epilogue: C/D map col=lane&15, row=(lane>>4)*4+reg  [m89]
#pragma unroll
    for (int fm = 0; fm < 4; ++fm) {
#pragma unroll
        for (int r = 0; r < 4; ++r) {
            int row = row0 + wm + fm * 16 + l4 * 4 + r;
            if (row < M) {
#pragma unroll
                for (int fn = 0; fn < 4; ++fn) {
                    int col = col0 + wn + fn * 16 + l15;
                    C[(size_t)row * N + col] = __float2half(acc[fm][fn][r]);
                }
            }
        }
    }
}

// ---------------- VALU GEMM (fallback path): C[M,N] = A[M,K] @ B[K,N] ----------------
template <typename TA, typename TC>
__global__ __launch_bounds__(256) void gemm_kernel(const TA* __restrict__ A,
                                                   const float* __restrict__ B,
                                                   TC* __restrict__ C,
                                                   int M, int N, int K) {
    __shared__ float As[16][64];
    __shared__ float Bs[16][64];
    const int tid  = threadIdx.x;
    const int row0 = blockIdx.y * 64, col0 = blockIdx.x * 64;
    const int am = tid >> 2, ak = (tid & 3) << 2;
    const int bk = tid >> 4, bn = (tid & 15) << 2;
    const int ty = (tid >> 4) << 2, tx = (tid & 15) << 2;
    float acc[4][4] = {};
    const int arow = row0 + am;
    for (int k0 = 0; k0 < K; k0 += 16) {
        float4 a4 = make_float4(0.f, 0.f, 0.f, 0.f);
        if (arow < M) a4 = ld4(A + (size_t)arow * K + k0 + ak);
        As[ak + 0][am] = a4.x; As[ak + 1][am] = a4.y;
        As[ak + 2][am] = a4.z; As[ak + 3][am] = a4.w;
        *(float4*)&Bs[bk][bn] = *(const float4*)(B + (size_t)(k0 + bk) * N + col0 + bn);
        __syncthreads();
#pragma unroll
        for (int k = 0; k < 16; ++k) {
            float4 ar = *(const float4*)&As[k][ty];
            float4 br = *(const float4*)&Bs[k][tx];
            acc[0][0] += ar.x * br.x; acc[0][1] += ar.x * br.y; acc[0][2] += ar.x * br.z; acc[0][3] += ar.x * br.w;
            acc[1][0] += ar.y * br.x; acc[1][1] += ar.y * br.y; acc[1][2] += ar.y * br.z; acc[1][3] += ar.y * br.w;
            acc[2][0] += ar.z * br.x; acc[2][1] += ar.z * br.y; acc[2][2] += ar.z * br.z; acc[2][3] += ar.z * br.w;
            acc[3][0] += ar.w * br.x; acc[3][1] += ar.w * br.y; acc[3][2] += ar.w * br.z; acc[3][3] += ar.w * br.w;
        }
        __syncthreads();
    }
#pragma unroll
    for (int i = 0; i < 4; ++i) {
        int r = row0 + ty + i;
        if (r < M) {
            float4 o = make_float4(acc[i][0], acc[i][1], acc[i][2], acc[i][3]);
            st4(C + (size_t)r * N + col0 + tx, o);
        }
    }
}

// ---------------- per-(node,head) attention logits ----------------
template <typename TH>
__global__ void al_kernel(const TH* __restrict__ ht, const float* __restrict__ a_src,
                          const float* __restrict__ a_dst, float* __restrict__ al_s,
                          float* __restrict__ al_d, int N, int C) {
    int wid  = (int)((blockIdx.x * blockDim.x + threadIdx.x) >> 6);
    int lane = threadIdx.x & 63;
    if (wid >= N * NHEADS) return;
    int n = wid / NHEADS, h = wid % NHEADS;
    const TH* hp = ht + (size_t)n * (NHEADS * C) + h * C;
    float ss = 0.f, sd = 0.f;
    for (int c = lane; c < C; c += 64) {
        float v = scl(hp[c]);
        ss += v * a_src[h * C + c];
        sd += v * a_dst[h * C + c];
    }
#pragma unroll
    for (int off = 32; off > 0; off >>= 1) {
        ss += __shfl_down(ss, off);
        sd += __shfl_down(sd, off);
    }
    if (lane == 0) { al_s[wid] = ss; al_d[wid] = sd; }
}

// ---------------- segment softmax (per dst node, per head) ----------------
__global__ void alpha_kernel(const int* __restrict__ offsets, const int* __restrict__ perm_src,
                             const float* __restrict__ al_s, const float* __restrict__ al_d,
                             float* __restrict__ alpha, int N) {
    int idx = blockIdx.x * blockDim.x + threadIdx.x;
    if (idx >= N * NHEADS) return;
    int n = idx / NHEADS, h = idx % NHEADS;
    int s = offsets[n], e = offsets[n + 1];
    float ad = al_d[idx];
    float m = -1e30f;
    for (int p = s; p < e; ++p) {
        float v = lrelu_f(al_s[perm_src[p] * NHEADS + h] + ad);
        m = fmaxf(m, v);
    }
    float denom = 0.f;
    for (int p = s; p < e; ++p) {
        float v  = lrelu_f(al_s[perm_src[p] * NHEADS + h] + ad);
        float ex = expf(v - m);
        alpha[(size_t)p * NHEADS + h] = ex;
        denom += ex;
    }
    float inv = 1.f / (denom + 1e-16f);
    for (int p = s; p < e; ++p) alpha[(size_t)p * NHEADS + h] *= inv;
}

// ---------------- alpha-weighted aggregation + epilogue ----------------
template <int HC, int C, int MODE, typename TH, typename TO>
__global__ __launch_bounds__(256) void agg_kernel(const TH* __restrict__ ht,
                                                  const float* __restrict__ alpha,
                                                  const int* __restrict__ offsets,
                                                  const int* __restrict__ perm_src,
                                                  const float* __restrict__ bias,
                                                  TO* __restrict__ out, int N) {
    constexpr int PER = HC / 256;
    int n = blockIdx.x;
    int tid = threadIdx.x;
    float acc[PER];
#pragma unroll
    for (int i = 0; i < PER; ++i) acc[i] = 0.f;
    int s = offsets[n], e = offsets[n + 1];
    for (int p = s; p < e; ++p) {
        int src = perm_src[p];
        const TH* hp = ht + (size_t)src * HC;
#pragma unroll
        for (int i = 0; i < PER; ++i) {
            int j = tid + i * 256;
            float a = alpha[(size_t)p * NHEADS + (j / C)];
            acc[i] += a * scl(hp[j]);
        }
    }
    if (MODE == 0) {
#pragma unroll
        for (int i = 0; i < PER; ++i) {
            int j = tid + i * 256;
            sst(&out[(size_t)n * HC + j], elu_f(acc[i] + bias[j]));
        }
    } else {
        float srow = 0.f;
#pragma unroll
        for (int i = 0; i < PER; ++i) srow += acc[i];
        sst(&out[(size_t)n * C + tid], elu_f(srow * (1.f / NHEADS) + bias[tid]));
    }
}

// ---------------- pooling ----------------
__global__ void gstart_kernel(const int* __restrict__ batch, int* __restrict__ gstart, int N) {
    int n = blockIdx.x * blockDim.x + threadIdx.x;
    if (n > N) return;
    if (n == 0) {
        int b0 = batch[0];
        for (int g = 0; g <= b0; ++g) gstart[g] = 0;
    } else if (n == N) {
        int bl = batch[N - 1];
        for (int g = bl + 1; g <= NG; ++g) gstart[g] = N;
    } else {
        int bp = batch[n - 1], bc = batch[n];
        for (int g = bp + 1; g <= bc; ++g) gstart[g] = n;
    }
}

__global__ void pool_kernel(const float* __restrict__ h5, const int* __restrict__ gstart,
                            float* __restrict__ pooled) {
    int g = blockIdx.x, c = threadIdx.x;  // 256 threads
    int s = gstart[g], e = gstart[g + 1];
    float sum = 0.f;
    for (int n = s; n < e; ++n) sum += h5[(size_t)n * 256 + c];
    float cnt = fmaxf((float)(e - s), 1.f);
    pooled[g * 256 + c] = elu_f(sum / cnt);
}

__global__ void linear_kernel(const float* __restrict__ pooled, const float* __restrict__ W,
                              const float* __restrict__ b, float* __restrict__ out) {
    int g = blockIdx.x, c = threadIdx.x;  // 128 threads
    float s = b[c];
    for (int k = 0; k < 256; ++k) s += pooled[g * 256 + k] * W[k * 128 + c];
    out[g * 128 + c] = s;
}

// ---------------- fallback pipeline (VALU GEMM, typed) ----------------
template <typename TIO, typename TH>
static void run_pipeline(const float* x, const float* const* W, const float* const* asrc,
                         const float* const* adst, const float* const* bias,
                         char* rawIO, char* rawHT,
                         float* al_s, float* al_d, float* alpha_buf,
                         const int* offsets, const int* perm_src,
                         int N, hipStream_t stream) {
    TIO* bufIO = (TIO*)rawIO;
    TH*  bufHT = (TH*)rawHT;
    {
        dim3 g(512 / 64, (N + 63) / 64);
        gemm_kernel<float, TH><<<g, 256, 0, stream>>>(x, W[0], bufHT, N, 512, 128);
        al_kernel<TH><<<(N * NHEADS * 64 + 255) / 256, 256, 0, stream>>>(bufHT, asrc[0], adst[0], al_s, al_d, N, 64);
        alpha_kernel<<<(N * NHEADS + 255) / 256, 256, 0, stream>>>(offsets, perm_src, al_s, al_d, alpha_buf, N);
        agg_kernel<512, 64, 0, TH, TIO><<<N, 256, 0, stream>>>(bufHT, alpha_buf, offsets, perm_src, bias[0], bufIO, N);
    }
    int Kdim = 512;
    for (int l = 1; l < 5; ++l) {
        dim3 g(2048 / 64, (N + 63) / 64);
        gemm_kernel<TIO, TH><<<g, 256, 0, stream>>>(bufIO, W[l], bufHT, N, 2048, Kdim);
        al_kernel<TH><<<(N * NHEADS * 64 + 255) / 256, 256, 0, stream>>>(bufHT, asrc[l], adst[l], al_s, al_d, N, 256);
        alpha_kernel<<<(N * NHEADS + 255) / 256, 256, 0, stream>>>(offsets, perm_src, al_s, al_d, alpha_buf, N);
        if (l < 4)
            agg_kernel<2048, 256, 0, TH, TIO><<<N, 256, 0, stream>>>(bufHT, alpha_buf, offsets, perm_src, bias[l], bufIO, N);
        else
            agg_kernel<2048, 256, 1, TH, float><<<N, 256, 0, stream>>>(bufHT, alpha_buf, offsets, perm_src, bias[l], (float*)rawIO, N);
        Kdim = 2048;
    }
}

// ---------------- host ----------------
extern "C" void kernel_launch(void* const* d_in, const int* in_sizes, int n_in,
                              void* d_out, int out_size, void* d_ws, size_t ws_size,
                              hipStream_t stream) {
    const float* x     = (const float*)d_in[0];
    const int*   ei    = (const int*)d_in[1];
    const int*   batch = (const int*)d_in[2];
    const float* W[5]    = {(const float*)d_in[3],  (const float*)d_in[7],  (const float*)d_in[11],
                            (const float*)d_in[15], (const float*)d_in[19]};
    const float* asrc[5] = {(const float*)d_in[4],  (const float*)d_in[8],  (const float*)d_in[12],
                            (const float*)d_in[16], (const float*)d_in[20]};
    const float* adst[5] = {(const float*)d_in[5],  (const float*)d_in[9],  (const float*)d_in[13],
                            (const float*)d_in[17], (const float*)d_in[21]};
    const float* bias[5] = {(const float*)d_in[6],  (const float*)d_in[10], (const float*)d_in[14],
                            (const float*)d_in[18], (const float*)d_in[22]};
    const float* Wlin = (const float*)d_in[23];
    const float* blin = (const float*)d_in[24];

    const int N    = in_sizes[0] / 128;
    const int E    = in_sizes[1] / 2;
    const int Etot = E + N;

    auto align256 = [](size_t b) { return (b + 255) & ~(size_t)255; };

    size_t sz_counts = align256((size_t)N * 4);
    size_t sz_off    = align256((size_t)(N + 1) * 4);
    size_t sz_cur    = align256((size_t)N * 4);
    size_t sz_perm   = align256((size_t)Etot * 4);
    size_t sz_al     = align256((size_t)N * NHEADS * 4);
    size_t sz_alpha  = align256((size_t)Etot * NHEADS * 4);
    size_t sz_gst    = align256((size_t)(NG + 1) * 4);
    size_t sz_pool   = align256((size_t)NG * 256 * 4);
    size_t misc = sz_counts + sz_off + sz_cur + sz_perm + 2 * sz_al + sz_alpha + sz_gst + sz_pool;

    size_t bigf  = align256((size_t)N * 2048 * sizeof(float));
    size_t bigh  = align256((size_t)N * 2048 * sizeof(__half));
    size_t sz_wt  = align256((size_t)2048 * 2048 * sizeof(__half));  // max W size
    size_t sz_x16 = align256((size_t)N * 128 * sizeof(__half));

    int path;
    if      (ws_size >= misc + 2 * bigh + sz_wt + sz_x16) path = 3;  // MFMA fp16 pipeline
    else if (ws_size >= misc + 2 * bigf)                  path = 0;
    else if (ws_size >= misc + bigf + bigh)               path = 1;
    else if (ws_size >= misc + 2 * bigh)                  path = 2;
    else {
        hipMemsetAsync(d_out, 0, (size_t)out_size * sizeof(float), stream);
        return;
    }

    char* ws = (char*)d_ws;
    size_t off = 0;
    auto carve = [&](size_t bytes) { void* p = ws + off; off += bytes; return p; };
    int*   counts   = (int*)carve(sz_counts);
    int*   offsets  = (int*)carve(sz_off);
    int*   cursor   = (int*)carve(sz_cur);
    int*   perm_src = (int*)carve(sz_perm);
    float* al_s     = (float*)carve(sz_al);
    float* al_d     = (float*)carve(sz_al);
    float* alpha    = (float*)carve(sz_alpha);
    int*   gstart   = (int*)carve(sz_gst);
    float* pooled   = (float*)carve(sz_pool);

    // CSR build
    hipMemsetAsync(counts, 0, (size_t)N * 4, stream);
    hist_kernel<<<(Etot + 255) / 256, 256, 0, stream>>>(ei, E, Etot, counts);
    scan_kernel<<<1, 256, 0, stream>>>(counts, offsets, cursor, N);
    scatter_kernel<<<(Etot + 255) / 256, 256, 0, stream>>>(ei, E, Etot, cursor, perm_src);

    if (path == 3) {
        char*   rawIO = (char*)carve(bigh);
        char*   rawHT = (char*)carve(bigh);
        __half* Wt    = (__half*)carve(sz_wt);
        __half* x16   = (__half*)carve(sz_x16);
        __half* bufIO = (__half*)rawIO;
        __half* bufHT = (__half*)rawHT;

        long n4 = (long)N * 128 / 4;
        f32_to_f16_kernel<<<(int)((n4 + 255) / 256), 256, 0, stream>>>(x, x16, n4);

        const __half* curA = x16;
        int Kdim = 128;
        for (int l = 0; l < 5; ++l) {
            const int C  = (l == 0) ? 64 : 256;
            const int HC = NHEADS * C;
            {
                dim3 tg(HC / 32, Kdim / 32);
                transpose_conv_kernel<<<tg, 256, 0, stream>>>(W[l], Wt, Kdim, HC);
            }
            {
                dim3 gg(HC / 128, (N + 127) / 128);
                gemm_mfma_kernel<<<gg, 256, 0, stream>>>(curA, Wt, bufHT, N, HC, Kdim);
            }
            al_kernel<__half><<<(N * NHEADS * 64 + 255) / 256, 256, 0, stream>>>(bufHT, asrc[l], adst[l], al_s, al_d, N, C);
            alpha_kernel<<<(N * NHEADS + 255) / 256, 256, 0, stream>>>(offsets, perm_src, al_s, al_d, alpha, N);
            if (l == 0)
                agg_kernel<512, 64, 0, __half, __half><<<N, 256, 0, stream>>>(bufHT, alpha, offsets, perm_src, bias[l], bufIO, N);
            else if (l < 4)
                agg_kernel<2048, 256, 0, __half, __half><<<N, 256, 0, stream>>>(bufHT, alpha, offsets, perm_src, bias[l], bufIO, N);
            else
                agg_kernel<2048, 256, 1, __half, float><<<N, 256, 0, stream>>>(bufHT, alpha, offsets, perm_src, bias[l], (float*)rawIO, N);
            curA = bufIO;
            Kdim = (l == 0) ? 512 : 2048;
        }
        gstart_kernel<<<(N + 1 + 255) / 256, 256, 0, stream>>>(batch, gstart, N);
        pool_kernel<<<NG, 256, 0, stream>>>((const float*)rawIO, gstart, pooled);
        linear_kernel<<<NG, 128, 0, stream>>>(pooled, Wlin, blin, (float*)d_out);
        return;
    }

    char* rawIO = (char*)carve(path == 2 ? bigh : bigf);
    char* rawHT = (char*)carve(path == 0 ? bigf : bigh);

    if (path == 0)
        run_pipeline<float, float>(x, W, asrc, adst, bias, rawIO, rawHT, al_s, al_d, alpha, offsets, perm_src, N, stream);
    else if (path == 1)
        run_pipeline<float, __half>(x, W, asrc, adst, bias, rawIO, rawHT, al_s, al_d, alpha, offsets, perm_src, N, stream);
    else
        run_pipeline<__half, __half>(x, W, asrc, adst, bias, rawIO, rawHT, al_s, al_d, alpha, offsets, perm_src, N, stream);

    gstart_kernel<<<(N + 1 + 255) / 256, 256, 0, stream>>>(batch, gstart, N);
    pool_kernel<<<NG, 256, 0, stream>>>((const float*)rawIO, gstart, pooled);
    linear_kernel<<<NG, 128, 0, stream>>>(pooled, Wlin, blin, (float*)d_out);
}

// Round 4
// 1424.595 us; speedup vs baseline: 6.5078x; 1.0364x over previous
//
#include <hip/hip_runtime.h>
#include <hip/hip_fp16.h>
#include <math.h>

#define NHEADS 8
#define NG 64

typedef _Float16 half8_t __attribute__((ext_vector_type(8)));
typedef _Float16 half4_t __attribute__((ext_vector_type(4)));
typedef float    float4_t __attribute__((ext_vector_type(4)));
typedef __attribute__((address_space(1))) const void g_void;
typedef __attribute__((address_space(3))) void l_void;

__device__ __forceinline__ float elu_f(float x)   { return x > 0.f ? x : expf(x) - 1.f; }
__device__ __forceinline__ float lrelu_f(float x) { return x >= 0.f ? x : 0.2f * x; }

// ---- typed 4-wide load/store + scalar converts (fp32 / fp16) ----
__device__ __forceinline__ float4 ld4(const float* p) { return *(const float4*)p; }
__device__ __forceinline__ float4 ld4(const __half* p) {
    const __half2* q = (const __half2*)p;
    __half2 a = q[0], b = q[1];
    return make_float4(__half2float(a.x), __half2float(a.y),
                       __half2float(b.x), __half2float(b.y));
}
__device__ __forceinline__ void st4(float* p, float4 v) { *(float4*)p = v; }
__device__ __forceinline__ void st4(__half* p, float4 v) {
    __half2 a, b;
    a.x = __float2half(v.x); a.y = __float2half(v.y);
    b.x = __float2half(v.z); b.y = __float2half(v.w);
    __half2* q = (__half2*)p; q[0] = a; q[1] = b;
}
__device__ __forceinline__ float scl(float v)  { return v; }
__device__ __forceinline__ float scl(__half v) { return __half2float(v); }
__device__ __forceinline__ void sst(float* p, float v)  { *p = v; }
__device__ __forceinline__ void sst(__half* p, float v) { *p = __float2half(v); }

// ---------------- CSR build (by dst) ----------------
__global__ void hist_kernel(const int* __restrict__ ei, int E, int Etot, int* __restrict__ counts) {
    int e = blockIdx.x * blockDim.x + threadIdx.x;
    if (e >= Etot) return;
    int dst = (e < E) ? ei[E + e] : (e - E);   // self-loop for e >= E
    atomicAdd(&counts[dst], 1);
}

__global__ void scan_kernel(const int* __restrict__ counts, int* __restrict__ offsets,
                            int* __restrict__ cursor, int N) {
    __shared__ int sdata[256];
    __shared__ int carry_s;
    if (threadIdx.x == 0) carry_s = 0;
    __syncthreads();
    for (int base = 0; base < N; base += 256) {
        int i = base + (int)threadIdx.x;
        int v = (i < N) ? counts[i] : 0;
        sdata[threadIdx.x] = v;
        __syncthreads();
        for (int off = 1; off < 256; off <<= 1) {
            int t = (threadIdx.x >= (unsigned)off) ? sdata[threadIdx.x - off] : 0;
            __syncthreads();
            sdata[threadIdx.x] += t;
            __syncthreads();
        }
        int excl = sdata[threadIdx.x] - v + carry_s;
        if (i < N) { offsets[i] = excl; cursor[i] = excl; }
        __syncthreads();
        if (threadIdx.x == 255) carry_s += sdata[255];
        __syncthreads();
    }
    if (threadIdx.x == 0) offsets[N] = carry_s;
}

__global__ void scatter_kernel(const int* __restrict__ ei, int E, int Etot,
                               int* __restrict__ cursor, int* __restrict__ perm_src) {
    int e = blockIdx.x * blockDim.x + threadIdx.x;
    if (e >= Etot) return;
    int src, dst;
    if (e < E) { src = ei[e]; dst = ei[E + e]; }
    else       { src = e - E; dst = e - E; }
    int pos = atomicAdd(&cursor[dst], 1);
    perm_src[pos] = src;
}

// ---------------- W[K][N] fp32 -> Wt[N][K] fp16 (tiled transpose) ----------------
__global__ __launch_bounds__(256) void transpose_conv_kernel(const float* __restrict__ W,
                                                             __half* __restrict__ Wt,
                                                             int K, int N) {
    __shared__ float t[32][33];
    int nb = blockIdx.x * 32, kb = blockIdx.y * 32;
    int tx = threadIdx.x & 31, ty = threadIdx.x >> 5;  // ty 0..7
#pragma unroll
    for (int r = 0; r < 32; r += 8)
        t[ty + r][tx] = W[(size_t)(kb + ty + r) * N + nb + tx];
    __syncthreads();
#pragma unroll
    for (int r = 0; r < 32; r += 8)
        Wt[(size_t)(nb + ty + r) * K + kb + tx] = __float2half(t[tx][ty + r]);
}

// ---------------- fp32 -> fp16 convert ----------------
struct h4s { __half a, b, c, d; };
__global__ void f32_to_f16_kernel(const float* __restrict__ in, __half* __restrict__ out, long n4) {
    long i = (long)blockIdx.x * blockDim.x + threadIdx.x;
    if (i >= n4) return;
    float4 v = ((const float4*)in)[i];
    h4s o; o.a = __float2half(v.x); o.b = __float2half(v.y);
    o.c = __float2half(v.z); o.d = __float2half(v.w);
    ((h4s*)out)[i] = o;
}

// ---------------- MFMA GEMM: C[M][N] = A[M][K] @ Bt[N][K]^T, all fp16 in, fp16 out ----
// 128x128 tile, BK=64, 4 waves (2x2 of 64x64), global_load_lds staging with
// XOR-swizzled global source + linear LDS dest; swizzled ds_read_b128 fragment reads.
// T1: bijective XCD-aware block swizzle (m204).
__global__ __launch_bounds__(256) void gemm_mfma_kernel(const __half* __restrict__ A,
                                                        const __half* __restrict__ Bt,
                                                        __half* __restrict__ C,
                                                        int M, int N, int K) {
    __shared__ __align__(16) __half Asm[128 * 64];
    __shared__ __align__(16) __half Bsm[128 * 64];
    const int tid  = threadIdx.x;
    const int lane = tid & 63;
    const int wave = tid >> 6;

    // XCD swizzle (bijective for any nwg)
    const int nwg = (int)(gridDim.x * gridDim.y);
    const int lin = (int)(blockIdx.y * gridDim.x + blockIdx.x);
    const int q = nwg >> 3, r = nwg & 7;
    const int xcd = lin & 7, idx = lin >> 3;
    const int nid = (xcd < r ? xcd * (q + 1) : r * (q + 1) + (xcd - r) * q) + idx;
    const int bx = nid % (int)gridDim.x;
    const int by = nid / (int)gridDim.x;
    const int row0 = by * 128;
    const int col0 = bx * 128;

    const int l15 = lane & 15;
    const int l4  = lane >> 4;            // 0..3
    const int wm  = (wave >> 1) * 64;     // wave's m offset in tile
    const int wn  = (wave & 1) * 64;      // wave's n offset in tile

    const int sl_row = lane >> 3;              // 0..7
    const int sl_kch = (lane & 7) ^ sl_row;    // logical k-chunk to fetch (XOR involution)

    float4_t acc[4][4];
#pragma unroll
    for (int i = 0; i < 4; ++i)
#pragma unroll
        for (int j = 0; j < 4; ++j)
            acc[i][j] = (float4_t){0.f, 0.f, 0.f, 0.f};

    for (int k0 = 0; k0 < K; k0 += 64) {
#pragma unroll
        for (int i = 0; i < 4; ++i) {
            int rr = (i * 4 + wave) * 8 + sl_row;     // 0..127
            int ar = row0 + rr; if (ar >= M) ar = M - 1;   // clamp (values unused)
            const __half* ga = A + (size_t)ar * K + k0 + sl_kch * 8;
            char* la = (char*)Asm + ((i * 4 + wave) * 1024 + lane * 16);
            __builtin_amdgcn_global_load_lds((g_void*)ga, (l_void*)la, 16, 0, 0);
            const __half* gb = Bt + (size_t)(col0 + rr) * K + k0 + sl_kch * 8;
            char* lb = (char*)Bsm + ((i * 4 + wave) * 1024 + lane * 16);
            __builtin_amdgcn_global_load_lds((g_void*)gb, (l_void*)lb, 16, 0, 0);
        }
        __syncthreads();
#pragma unroll
        for (int kh = 0; kh < 2; ++kh) {
            half8_t af[4], bf[4];
#pragma unroll
            for (int f = 0; f < 4; ++f) {
                int rowa = wm + f * 16 + l15;
                int ca = (kh * 4 + l4) ^ (rowa & 7);
                af[f] = *(const half8_t*)((const char*)Asm + rowa * 128 + ca * 16);
                int rowb = wn + f * 16 + l15;
                int cb = (kh * 4 + l4) ^ (rowb & 7);
                bf[f] = *(const half8_t*)((const char*)Bsm + rowb * 128 + cb * 16);
            }
#pragma unroll
            for (int fm = 0; fm < 4; ++fm)
#pragma unroll
                for (int fn = 0; fn < 4; ++fn)
                    acc[fm][fn] = __builtin_amdgcn_mfma_f32_16x16x32_f16(af[fm], bf[fn], acc[fm][fn], 0, 0, 0);
        }
        __syncthreads();
    }

    // epilogue: C/D map col=lane&15, row=(lane>>4)*4+reg  [m89]
#pragma unroll
    for (int fm = 0; fm < 4; ++fm) {
#pragma unroll
        for (int r2 = 0; r2 < 4; ++r2) {
            int row = row0 + wm + fm * 16 + l4 * 4 + r2;
            if (row < M) {
#pragma unroll
                for (int fn = 0; fn < 4; ++fn) {
                    int col = col0 + wn + fn * 16 + l15;
                    C[(size_t)row * N + col] = __float2half(acc[fm][fn][r2]);
                }
            }
        }
    }
}

// ---------------- VALU GEMM (fallback path): C[M,N] = A[M,K] @ B[K,N] ----------------
template <typename TA, typename TC>
__global__ __launch_bounds__(256) void gemm_kernel(const TA* __restrict__ A,
                                                   const float* __restrict__ B,
                                                   TC* __restrict__ C,
                                                   int M, int N, int K) {
    __shared__ float As[16][64];
    __shared__ float Bs[16][64];
    const int tid  = threadIdx.x;
    const int row0 = blockIdx.y * 64, col0 = blockIdx.x * 64;
    const int am = tid >> 2, ak = (tid & 3) << 2;
    const int bk = tid >> 4, bn = (tid & 15) << 2;
    const int ty = (tid >> 4) << 2, tx = (tid & 15) << 2;
    float acc[4][4] = {};
    const int arow = row0 + am;
    for (int k0 = 0; k0 < K; k0 += 16) {
        float4 a4 = make_float4(0.f, 0.f, 0.f, 0.f);
        if (arow < M) a4 = ld4(A + (size_t)arow * K + k0 + ak);
        As[ak + 0][am] = a4.x; As[ak + 1][am] = a4.y;
        As[ak + 2][am] = a4.z; As[ak + 3][am] = a4.w;
        *(float4*)&Bs[bk][bn] = *(const float4*)(B + (size_t)(k0 + bk) * N + col0 + bn);
        __syncthreads();
#pragma unroll
        for (int k = 0; k < 16; ++k) {
            float4 ar = *(const float4*)&As[k][ty];
            float4 br = *(const float4*)&Bs[k][tx];
            acc[0][0] += ar.x * br.x; acc[0][1] += ar.x * br.y; acc[0][2] += ar.x * br.z; acc[0][3] += ar.x * br.w;
            acc[1][0] += ar.y * br.x; acc[1][1] += ar.y * br.y; acc[1][2] += ar.y * br.z; acc[1][3] += ar.y * br.w;
            acc[2][0] += ar.z * br.x; acc[2][1] += ar.z * br.y; acc[2][2] += ar.z * br.z; acc[2][3] += ar.z * br.w;
            acc[3][0] += ar.w * br.x; acc[3][1] += ar.w * br.y; acc[3][2] += ar.w * br.z; acc[3][3] += ar.w * br.w;
        }
        __syncthreads();
    }
#pragma unroll
    for (int i = 0; i < 4; ++i) {
        int r = row0 + ty + i;
        if (r < M) {
            float4 o = make_float4(acc[i][0], acc[i][1], acc[i][2], acc[i][3]);
            st4(C + (size_t)r * N + col0 + tx, o);
        }
    }
}

// ---------------- attention logits, vectorized (fp16 ht) ----------------
template <int C>
__global__ void al_vec_kernel(const __half* __restrict__ ht, const float* __restrict__ a_src,
                              const float* __restrict__ a_dst, float* __restrict__ al_s,
                              float* __restrict__ al_d, int N) {
    int wid  = (int)((blockIdx.x * blockDim.x + threadIdx.x) >> 6);
    int lane = threadIdx.x & 63;
    if (wid >= N * NHEADS) return;
    int n = wid / NHEADS, h = wid % NHEADS;
    float ss = 0.f, sd = 0.f;
    int c0 = lane * 4;
    if (c0 < C) {
        const __half* hp = ht + (size_t)n * (NHEADS * C) + h * C + c0;
        half4_t v = *(const half4_t*)hp;
        float4 as4 = *(const float4*)(a_src + h * C + c0);
        float4 ad4 = *(const float4*)(a_dst + h * C + c0);
        float v0 = (float)v[0], v1 = (float)v[1], v2 = (float)v[2], v3 = (float)v[3];
        ss = v0 * as4.x + v1 * as4.y + v2 * as4.z + v3 * as4.w;
        sd = v0 * ad4.x + v1 * ad4.y + v2 * ad4.z + v3 * ad4.w;
    }
#pragma unroll
    for (int off = 32; off > 0; off >>= 1) {
        ss += __shfl_down(ss, off);
        sd += __shfl_down(sd, off);
    }
    if (lane == 0) { al_s[wid] = ss; al_d[wid] = sd; }
}

// ---------------- segment softmax, per-node all-heads; alpha stored UNNORMALIZED ----
// inv_d[n*8+h] = 1/(denom+1e-16) is applied in agg (constant over the dst segment).
__global__ void alpha_node_kernel(const int* __restrict__ offsets, const int* __restrict__ perm_src,
                                  const float* __restrict__ al_s, const float* __restrict__ al_d,
                                  float* __restrict__ alpha, float* __restrict__ inv_d, int N) {
    int n = blockIdx.x * blockDim.x + threadIdx.x;
    if (n >= N) return;
    int s = offsets[n], e = offsets[n + 1];
    float ad[8], m[8], den[8];
    {
        float4 d0 = *(const float4*)(al_d + (size_t)n * 8);
        float4 d1 = *(const float4*)(al_d + (size_t)n * 8 + 4);
        ad[0] = d0.x; ad[1] = d0.y; ad[2] = d0.z; ad[3] = d0.w;
        ad[4] = d1.x; ad[5] = d1.y; ad[6] = d1.z; ad[7] = d1.w;
    }
#pragma unroll
    for (int h = 0; h < 8; ++h) { m[h] = -1e30f; den[h] = 0.f; }
    for (int p = s; p < e; ++p) {
        int src = perm_src[p];
        float4 s0 = *(const float4*)(al_s + (size_t)src * 8);
        float4 s1 = *(const float4*)(al_s + (size_t)src * 8 + 4);
        float as8[8] = {s0.x, s0.y, s0.z, s0.w, s1.x, s1.y, s1.z, s1.w};
#pragma unroll
        for (int h = 0; h < 8; ++h) m[h] = fmaxf(m[h], lrelu_f(as8[h] + ad[h]));
    }
    for (int p = s; p < e; ++p) {
        int src = perm_src[p];
        float4 s0 = *(const float4*)(al_s + (size_t)src * 8);
        float4 s1 = *(const float4*)(al_s + (size_t)src * 8 + 4);
        float as8[8] = {s0.x, s0.y, s0.z, s0.w, s1.x, s1.y, s1.z, s1.w};
        float ex8[8];
#pragma unroll
        for (int h = 0; h < 8; ++h) {
            float ex = expf(lrelu_f(as8[h] + ad[h]) - m[h]);
            ex8[h] = ex; den[h] += ex;
        }
        float4* ap = (float4*)(alpha + (size_t)p * 8);
        ap[0] = make_float4(ex8[0], ex8[1], ex8[2], ex8[3]);
        ap[1] = make_float4(ex8[4], ex8[5], ex8[6], ex8[7]);
    }
    float4* ip = (float4*)(inv_d + (size_t)n * 8);
    ip[0] = make_float4(1.f / (den[0] + 1e-16f), 1.f / (den[1] + 1e-16f),
                        1.f / (den[2] + 1e-16f), 1.f / (den[3] + 1e-16f));
    ip[1] = make_float4(1.f / (den[4] + 1e-16f), 1.f / (den[5] + 1e-16f),
                        1.f / (den[6] + 1e-16f), 1.f / (den[7] + 1e-16f));
}

// ---------------- aggregation, vectorized (fp16 ht), unnormalized alpha + inv ------
// MODE 0: out[n,j] = elu(inv[head(j)] * acc[j] + bias[j])      (__half out)
// MODE 1: out[n,c] = elu(mean_h inv[h]*acc[h*C+c] + bias[c])   (float out)
template <int HC, int C, int MODE>
__global__ __launch_bounds__(256) void agg_vec_kernel(const __half* __restrict__ ht,
                                                      const float* __restrict__ alpha,
                                                      const float* __restrict__ inv_d,
                                                      const int* __restrict__ offsets,
                                                      const int* __restrict__ perm_src,
                                                      const float* __restrict__ bias,
                                                      void* __restrict__ outv, int N) {
    constexpr int V = HC / 256;          // 2 (HC=512) or 8 (HC=2048)
    int n = blockIdx.x;
    int tid = threadIdx.x;
    const int head = (tid * V) / C;      // constant per thread
    float acc[V];
#pragma unroll
    for (int i = 0; i < V; ++i) acc[i] = 0.f;
    int s = offsets[n], e = offsets[n + 1];
    const __half* base = ht + (size_t)tid * V;
    for (int p = s; p < e; ++p) {
        int src = perm_src[p];
        float a = alpha[(size_t)p * NHEADS + head];
        const __half* hp = base + (size_t)src * HC;
        if (V == 8) {
            half8_t v = *(const half8_t*)hp;
#pragma unroll
            for (int i = 0; i < 8; ++i) acc[i] += a * (float)v[i];
        } else {
            __half2 v2 = *(const __half2*)hp;
            acc[0] += a * __half2float(v2.x);
            acc[1] += a * __half2float(v2.y);
        }
    }
    float inv = inv_d[(size_t)n * NHEADS + head];
    if (MODE == 0) {
        __half* out = (__half*)outv;
        if (V == 8) {
            half8_t o;
#pragma unroll
            for (int i = 0; i < 8; ++i)
                o[i] = (_Float16)elu_f(acc[i] * inv + bias[tid * 8 + i]);
            *(half8_t*)(out + (size_t)n * HC + tid * 8) = o;
        } else {
            __half2 o;
            o.x = __float2half(elu_f(acc[0] * inv + bias[tid * 2 + 0]));
            o.y = __float2half(elu_f(acc[1] * inv + bias[tid * 2 + 1]));
            *(__half2*)(out + (size_t)n * HC + tid * 2) = o;
        }
    } else {
        // V==8, C=256: LDS transpose-reduce over heads
        __shared__ float sm[256][8];
#pragma unroll
        for (int i = 0; i < 8; ++i) sm[tid][i] = acc[i] * inv;
        __syncthreads();
        float ssum = 0.f;
#pragma unroll
        for (int h = 0; h < 8; ++h) ssum += sm[h * 32 + (tid >> 3)][tid & 7];
        float* out = (float*)outv;
        out[(size_t)n * C + tid] = elu_f(ssum * (1.f / NHEADS) + bias[tid]);
    }
}

// ---------------- fallback scalar kernels (paths 0-2) ----------------
template <typename TH>
__global__ void al_kernel(const TH* __restrict__ ht, const float* __restrict__ a_src,
                          const float* __restrict__ a_dst, float* __restrict__ al_s,
                          float* __restrict__ al_d, int N, int C) {
    int wid  = (int)((blockIdx.x * blockDim.x + threadIdx.x) >> 6);
    int lane = threadIdx.x & 63;
    if (wid >= N * NHEADS) return;
    int n = wid / NHEADS, h = wid % NHEADS;
    const TH* hp = ht + (size_t)n * (NHEADS * C) + h * C;
    float ss = 0.f, sd = 0.f;
    for (int c = lane; c < C; c += 64) {
        float v = scl(hp[c]);
        ss += v * a_src[h * C + c];
        sd += v * a_dst[h * C + c];
    }
#pragma unroll
    for (int off = 32; off > 0; off >>= 1) {
        ss += __shfl_down(ss, off);
        sd += __shfl_down(sd, off);
    }
    if (lane == 0) { al_s[wid] = ss; al_d[wid] = sd; }
}

__global__ void alpha_kernel(const int* __restrict__ offsets, const int* __restrict__ perm_src,
                             const float* __restrict__ al_s, const float* __restrict__ al_d,
                             float* __restrict__ alpha, int N) {
    int idx = blockIdx.x * blockDim.x + threadIdx.x;
    if (idx >= N * NHEADS) return;
    int n = idx / NHEADS, h = idx % NHEADS;
    int s = offsets[n], e = offsets[n + 1];
    float ad = al_d[idx];
    float m = -1e30f;
    for (int p = s; p < e; ++p) {
        float v = lrelu_f(al_s[perm_src[p] * NHEADS + h] + ad);
        m = fmaxf(m, v);
    }
    float denom = 0.f;
    for (int p = s; p < e; ++p) {
        float v  = lrelu_f(al_s[perm_src[p] * NHEADS + h] + ad);
        float ex = expf(v - m);
        alpha[(size_t)p * NHEADS + h] = ex;
        denom += ex;
    }
    float inv = 1.f / (denom + 1e-16f);
    for (int p = s; p < e; ++p) alpha[(size_t)p * NHEADS + h] *= inv;
}

template <int HC, int C, int MODE, typename TH, typename TO>
__global__ __launch_bounds__(256) void agg_kernel(const TH* __restrict__ ht,
                                                  const float* __restrict__ alpha,
                                                  const int* __restrict__ offsets,
                                                  const int* __restrict__ perm_src,
                                                  const float* __restrict__ bias,
                                                  TO* __restrict__ out, int N) {
    constexpr int PER = HC / 256;
    int n = blockIdx.x;
    int tid = threadIdx.x;
    float acc[PER];
#pragma unroll
    for (int i = 0; i < PER; ++i) acc[i] = 0.f;
    int s = offsets[n], e = offsets[n + 1];
    for (int p = s; p < e; ++p) {
        int src = perm_src[p];
        const TH* hp = ht + (size_t)src * HC;
#pragma unroll
        for (int i = 0; i < PER; ++i) {
            int j = tid + i * 256;
            float a = alpha[(size_t)p * NHEADS + (j / C)];
            acc[i] += a * scl(hp[j]);
        }
    }
    if (MODE == 0) {
#pragma unroll
        for (int i = 0; i < PER; ++i) {
            int j = tid + i * 256;
            sst(&out[(size_t)n * HC + j], elu_f(acc[i] + bias[j]));
        }
    } else {
        float srow = 0.f;
#pragma unroll
        for (int i = 0; i < PER; ++i) srow += acc[i];
        sst(&out[(size_t)n * C + tid], elu_f(srow * (1.f / NHEADS) + bias[tid]));
    }
}

// ---------------- pooling ----------------
__global__ void gstart_kernel(const int* __restrict__ batch, int* __restrict__ gstart, int N) {
    int n = blockIdx.x * blockDim.x + threadIdx.x;
    if (n > N) return;
    if (n == 0) {
        int b0 = batch[0];
        for (int g = 0; g <= b0; ++g) gstart[g] = 0;
    } else if (n == N) {
        int bl = batch[N - 1];
        for (int g = bl + 1; g <= NG; ++g) gstart[g] = N;
    } else {
        int bp = batch[n - 1], bc = batch[n];
        for (int g = bp + 1; g <= bc; ++g) gstart[g] = n;
    }
}

__global__ void pool_kernel(const float* __restrict__ h5, const int* __restrict__ gstart,
                            float* __restrict__ pooled) {
    int g = blockIdx.x, c = threadIdx.x;  // 256 threads
    int s = gstart[g], e = gstart[g + 1];
    float sum = 0.f;
    for (int n = s; n < e; ++n) sum += h5[(size_t)n * 256 + c];
    float cnt = fmaxf((float)(e - s), 1.f);
    pooled[g * 256 + c] = elu_f(sum / cnt);
}

__global__ void linear_kernel(const float* __restrict__ pooled, const float* __restrict__ W,
                              const float* __restrict__ b, float* __restrict__ out) {
    int g = blockIdx.x, c = threadIdx.x;  // 128 threads
    float s = b[c];
    for (int k = 0; k < 256; ++k) s += pooled[g * 256 + k] * W[k * 128 + c];
    out[g * 128 + c] = s;
}

// ---------------- fallback pipeline (VALU GEMM, typed) ----------------
template <typename TIO, typename TH>
static void run_pipeline(const float* x, const float* const* W, const float* const* asrc,
                         const float* const* adst, const float* const* bias,
                         char* rawIO, char* rawHT,
                         float* al_s, float* al_d, float* alpha_buf,
                         const int* offsets, const int* perm_src,
                         int N, hipStream_t stream) {
    TIO* bufIO = (TIO*)rawIO;
    TH*  bufHT = (TH*)rawHT;
    {
        dim3 g(512 / 64, (N + 63) / 64);
        gemm_kernel<float, TH><<<g, 256, 0, stream>>>(x, W[0], bufHT, N, 512, 128);
        al_kernel<TH><<<(N * NHEADS * 64 + 255) / 256, 256, 0, stream>>>(bufHT, asrc[0], adst[0], al_s, al_d, N, 64);
        alpha_kernel<<<(N * NHEADS + 255) / 256, 256, 0, stream>>>(offsets, perm_src, al_s, al_d, alpha_buf, N);
        agg_kernel<512, 64, 0, TH, TIO><<<N, 256, 0, stream>>>(bufHT, alpha_buf, offsets, perm_src, bias[0], bufIO, N);
    }
    int Kdim = 512;
    for (int l = 1; l < 5; ++l) {
        dim3 g(2048 / 64, (N + 63) / 64);
        gemm_kernel<TIO, TH><<<g, 256, 0, stream>>>(bufIO, W[l], bufHT, N, 2048, Kdim);
        al_kernel<TH><<<(N * NHEADS * 64 + 255) / 256, 256, 0, stream>>>(bufHT, asrc[l], adst[l], al_s, al_d, N, 256);
        alpha_kernel<<<(N * NHEADS + 255) / 256, 256, 0, stream>>>(offsets, perm_src, al_s, al_d, alpha_buf, N);
        if (l < 4)
            agg_kernel<2048, 256, 0, TH, TIO><<<N, 256, 0, stream>>>(bufHT, alpha_buf, offsets, perm_src, bias[l], bufIO, N);
        else
            agg_kernel<2048, 256, 1, TH, float><<<N, 256, 0, stream>>>(bufHT, alpha_buf, offsets, perm_src, bias[l], (float*)rawIO, N);
        Kdim = 2048;
    }
}

// ---------------- host ----------------
extern "C" void kernel_launch(void* const* d_in, const int* in_sizes, int n_in,
                              void* d_out, int out_size, void* d_ws, size_t ws_size,
                              hipStream_t stream) {
    const float* x     = (const float*)d_in[0];
    const int*   ei    = (const int*)d_in[1];
    const int*   batch = (const int*)d_in[2];
    const float* W[5]    = {(const float*)d_in[3],  (const float*)d_in[7],  (const float*)d_in[11],
                            (const float*)d_in[15], (const float*)d_in[19]};
    const float* asrc[5] = {(const float*)d_in[4],  (const float*)d_in[8],  (const float*)d_in[12],
                            (const float*)d_in[16], (const float*)d_in[20]};
    const float* adst[5] = {(const float*)d_in[5],  (const float*)d_in[9],  (const float*)d_in[13],
                            (const float*)d_in[17], (const float*)d_in[21]};
    const float* bias[5] = {(const float*)d_in[6],  (const float*)d_in[10], (const float*)d_in[14],
                            (const float*)d_in[18], (const float*)d_in[22]};
    const float* Wlin = (const float*)d_in[23];
    const float* blin = (const float*)d_in[24];

    const int N    = in_sizes[0] / 128;
    const int E    = in_sizes[1] / 2;
    const int Etot = E + N;

    auto align256 = [](size_t b) { return (b + 255) & ~(size_t)255; };

    size_t sz_counts = align256((size_t)N * 4);
    size_t sz_off    = align256((size_t)(N + 1) * 4);
    size_t sz_cur    = align256((size_t)N * 4);
    size_t sz_perm   = align256((size_t)Etot * 4);
    size_t sz_al     = align256((size_t)N * NHEADS * 4);
    size_t sz_alpha  = align256((size_t)Etot * NHEADS * 4);
    size_t sz_inv    = align256((size_t)N * NHEADS * 4);
    size_t sz_gst    = align256((size_t)(NG + 1) * 4);
    size_t sz_pool   = align256((size_t)NG * 256 * 4);
    size_t misc = sz_counts + sz_off + sz_cur + sz_perm + 2 * sz_al + sz_alpha + sz_inv + sz_gst + sz_pool;

    size_t bigf  = align256((size_t)N * 2048 * sizeof(float));
    size_t bigh  = align256((size_t)N * 2048 * sizeof(__half));
    size_t sz_wt  = align256((size_t)2048 * 2048 * sizeof(__half));  // max W size
    size_t sz_x16 = align256((size_t)N * 128 * sizeof(__half));

    int path;
    if      (ws_size >= misc + 2 * bigh + sz_wt + sz_x16) path = 3;  // MFMA fp16 pipeline
    else if (ws_size >= misc + 2 * bigf)                  path = 0;
    else if (ws_size >= misc + bigf + bigh)               path = 1;
    else if (ws_size >= misc + 2 * bigh)                  path = 2;
    else {
        hipMemsetAsync(d_out, 0, (size_t)out_size * sizeof(float), stream);
        return;
    }

    char* ws = (char*)d_ws;
    size_t off = 0;
    auto carve = [&](size_t bytes) { void* p = ws + off; off += bytes; return p; };
    int*   counts   = (int*)carve(sz_counts);
    int*   offsets  = (int*)carve(sz_off);
    int*   cursor   = (int*)carve(sz_cur);
    int*   perm_src = (int*)carve(sz_perm);
    float* al_s     = (float*)carve(sz_al);
    float* al_d     = (float*)carve(sz_al);
    float* alpha    = (float*)carve(sz_alpha);
    float* inv_d    = (float*)carve(sz_inv);
    int*   gstart   = (int*)carve(sz_gst);
    float* pooled   = (float*)carve(sz_pool);

    // CSR build
    hipMemsetAsync(counts, 0, (size_t)N * 4, stream);
    hist_kernel<<<(Etot + 255) / 256, 256, 0, stream>>>(ei, E, Etot, counts);
    scan_kernel<<<1, 256, 0, stream>>>(counts, offsets, cursor, N);
    scatter_kernel<<<(Etot + 255) / 256, 256, 0, stream>>>(ei, E, Etot, cursor, perm_src);

    if (path == 3) {
        char*   rawIO = (char*)carve(bigh);
        char*   rawHT = (char*)carve(bigh);
        __half* Wt    = (__half*)carve(sz_wt);
        __half* x16   = (__half*)carve(sz_x16);
        __half* bufIO = (__half*)rawIO;
        __half* bufHT = (__half*)rawHT;

        long n4 = (long)N * 128 / 4;
        f32_to_f16_kernel<<<(int)((n4 + 255) / 256), 256, 0, stream>>>(x, x16, n4);

        const __half* curA = x16;
        int Kdim = 128;
        for (int l = 0; l < 5; ++l) {
            const int C  = (l == 0) ? 64 : 256;
            const int HC = NHEADS * C;
            {
                dim3 tg(HC / 32, Kdim / 32);
                transpose_conv_kernel<<<tg, 256, 0, stream>>>(W[l], Wt, Kdim, HC);
            }
            {
                dim3 gg(HC / 128, (N + 127) / 128);
                gemm_mfma_kernel<<<gg, 256, 0, stream>>>(curA, Wt, bufHT, N, HC, Kdim);
            }
            if (l == 0)
                al_vec_kernel<64><<<(N * NHEADS * 64 + 255) / 256, 256, 0, stream>>>(bufHT, asrc[l], adst[l], al_s, al_d, N);
            else
                al_vec_kernel<256><<<(N * NHEADS * 64 + 255) / 256, 256, 0, stream>>>(bufHT, asrc[l], adst[l], al_s, al_d, N);
            alpha_node_kernel<<<(N + 255) / 256, 256, 0, stream>>>(offsets, perm_src, al_s, al_d, alpha, inv_d, N);
            if (l == 0)
                agg_vec_kernel<512, 64, 0><<<N, 256, 0, stream>>>(bufHT, alpha, inv_d, offsets, perm_src, bias[l], bufIO, N);
            else if (l < 4)
                agg_vec_kernel<2048, 256, 0><<<N, 256, 0, stream>>>(bufHT, alpha, inv_d, offsets, perm_src, bias[l], bufIO, N);
            else
                agg_vec_kernel<2048, 256, 1><<<N, 256, 0, stream>>>(bufHT, alpha, inv_d, offsets, perm_src, bias[l], (float*)rawIO, N);
            curA = bufIO;
            Kdim = (l == 0) ? 512 : 2048;
        }
        gstart_kernel<<<(N + 1 + 255) / 256, 256, 0, stream>>>(batch, gstart, N);
        pool_kernel<<<NG, 256, 0, stream>>>((const float*)rawIO, gstart, pooled);
        linear_kernel<<<NG, 128, 0, stream>>>(pooled, Wlin, blin, (float*)d_out);
        return;
    }

    char* rawIO = (char*)carve(path == 2 ? bigh : bigf);
    char* rawHT = (char*)carve(path == 0 ? bigf : bigh);

    if (path == 0)
        run_pipeline<float, float>(x, W, asrc, adst, bias, rawIO, rawHT, al_s, al_d, alpha, offsets, perm_src, N, stream);
    else if (path == 1)
        run_pipeline<float, __half>(x, W, asrc, adst, bias, rawIO, rawHT, al_s, al_d, alpha, offsets, perm_src, N, stream);
    else
        run_pipeline<__half, __half>(x, W, asrc, adst, bias, rawIO, rawHT, al_s, al_d, alpha, offsets, perm_src, N, stream);

    gstart_kernel<<<(N + 1 + 255) / 256, 256, 0, stream>>>(batch, gstart, N);
    pool_kernel<<<NG, 256, 0, stream>>>((const float*)rawIO, gstart, pooled);
    linear_kernel<<<NG, 128, 0, stream>>>(pooled, Wlin, blin, (float*)d_out);
}

// Round 5
// 1283.558 us; speedup vs baseline: 7.2228x; 1.1099x over previous
//
#include <hip/hip_runtime.h>
#include <hip/hip_fp16.h>
#include <math.h>

#define NHEADS 8
#define NG 64

typedef _Float16 half8_t __attribute__((ext_vector_type(8)));
typedef _Float16 half4_t __attribute__((ext_vector_type(4)));
typedef float    float4_t __attribute__((ext_vector_type(4)));
typedef __attribute__((address_space(1))) const void g_void;
typedef __attribute__((address_space(3))) void l_void;

__device__ __forceinline__ float elu_f(float x)   { return x > 0.f ? x : expf(x) - 1.f; }
__device__ __forceinline__ float lrelu_f(float x) { return x >= 0.f ? x : 0.2f * x; }

// ---- typed 4-wide load/store + scalar converts (fp32 / fp16) ----
__device__ __forceinline__ float4 ld4(const float* p) { return *(const float4*)p; }
__device__ __forceinline__ float4 ld4(const __half* p) {
    const __half2* q = (const __half2*)p;
    __half2 a = q[0], b = q[1];
    return make_float4(__half2float(a.x), __half2float(a.y),
                       __half2float(b.x), __half2float(b.y));
}
__device__ __forceinline__ void st4(float* p, float4 v) { *(float4*)p = v; }
__device__ __forceinline__ void st4(__half* p, float4 v) {
    __half2 a, b;
    a.x = __float2half(v.x); a.y = __float2half(v.y);
    b.x = __float2half(v.z); b.y = __float2half(v.w);
    __half2* q = (__half2*)p; q[0] = a; q[1] = b;
}
__device__ __forceinline__ float scl(float v)  { return v; }
__device__ __forceinline__ float scl(__half v) { return __half2float(v); }
__device__ __forceinline__ void sst(float* p, float v)  { *p = v; }
__device__ __forceinline__ void sst(__half* p, float v) { *p = __float2half(v); }

struct h4s { __half a, b, c, d; };

// ---------------- CSR build (by dst) ----------------
__global__ void hist_kernel(const int* __restrict__ ei, int E, int Etot, int* __restrict__ counts) {
    int e = blockIdx.x * blockDim.x + threadIdx.x;
    if (e >= Etot) return;
    int dst = (e < E) ? ei[E + e] : (e - E);   // self-loop for e >= E
    atomicAdd(&counts[dst], 1);
}

// single-block shuffle scan, 1024 elems/iter, 2 barriers/iter
__global__ __launch_bounds__(256) void scan_kernel(const int* __restrict__ counts,
                                                   int* __restrict__ offsets,
                                                   int* __restrict__ cursor, int N) {
    __shared__ int wsum[4];
    const int tid = threadIdx.x;
    const int lane = tid & 63, wid = tid >> 6;
    int carry = 0;
    for (int base = 0; base < N; base += 1024) {
        int i0 = base + tid * 4;
        int v0 = 0, v1 = 0, v2 = 0, v3 = 0;
        if (i0 + 3 < N) {
            int4 q = *(const int4*)(counts + i0);
            v0 = q.x; v1 = q.y; v2 = q.z; v3 = q.w;
        } else {
            if (i0     < N) v0 = counts[i0];
            if (i0 + 1 < N) v1 = counts[i0 + 1];
            if (i0 + 2 < N) v2 = counts[i0 + 2];
            if (i0 + 3 < N) v3 = counts[i0 + 3];
        }
        int tsum = v0 + v1 + v2 + v3;
        int incl = tsum;
#pragma unroll
        for (int off = 1; off < 64; off <<= 1) {
            int t = __shfl_up(incl, off);
            if (lane >= off) incl += t;
        }
        if (lane == 63) wsum[wid] = incl;
        __syncthreads();
        int woff = carry;
        for (int w = 0; w < wid; ++w) woff += wsum[w];
        int o0 = woff + incl - tsum;
        int o1 = o0 + v0, o2 = o1 + v1, o3 = o2 + v2;
        if (i0     < N) { offsets[i0]     = o0; cursor[i0]     = o0; }
        if (i0 + 1 < N) { offsets[i0 + 1] = o1; cursor[i0 + 1] = o1; }
        if (i0 + 2 < N) { offsets[i0 + 2] = o2; cursor[i0 + 2] = o2; }
        if (i0 + 3 < N) { offsets[i0 + 3] = o3; cursor[i0 + 3] = o3; }
        __syncthreads();
        carry += wsum[0] + wsum[1] + wsum[2] + wsum[3];
    }
    if (tid == 0) offsets[N] = carry;
}

__global__ void scatter_kernel(const int* __restrict__ ei, int E, int Etot,
                               int* __restrict__ cursor, int* __restrict__ perm_src) {
    int e = blockIdx.x * blockDim.x + threadIdx.x;
    if (e >= Etot) return;
    int src, dst;
    if (e < E) { src = ei[e]; dst = ei[E + e]; }
    else       { src = e - E; dst = e - E; }
    int pos = atomicAdd(&cursor[dst], 1);
    perm_src[pos] = src;
}

// ---------------- fused prep: x->fp16 convert + 5 weight transposes ----------------
struct PrepArgs {
    const float* x; __half* x16; long n4;
    const float* W0; const float* W1; const float* W2; const float* W3; const float* W4;
    __half* T0; __half* T1; __half* T2; __half* T3; __half* T4;
    int K0, K1, K2, K3, K4;
    int N0, N1, N2, N3, N4;
    int b0, b1, b2, b3, b4, b5;   // cumulative block ends: conv, t0..t4
};

__global__ __launch_bounds__(256) void prep_kernel(PrepArgs a) {
    int bid = blockIdx.x;
    if (bid < a.b0) {
        long i = (long)bid * 256 + threadIdx.x;
        if (i < a.n4) {
            float4 v = ((const float4*)a.x)[i];
            h4s o; o.a = __float2half(v.x); o.b = __float2half(v.y);
            o.c = __float2half(v.z); o.d = __float2half(v.w);
            ((h4s*)a.x16)[i] = o;
        }
        return;
    }
    const float* W; __half* T; int K, Nn, t;
    if      (bid < a.b1) { W = a.W0; T = a.T0; K = a.K0; Nn = a.N0; t = bid - a.b0; }
    else if (bid < a.b2) { W = a.W1; T = a.T1; K = a.K1; Nn = a.N1; t = bid - a.b1; }
    else if (bid < a.b3) { W = a.W2; T = a.T2; K = a.K2; Nn = a.N2; t = bid - a.b2; }
    else if (bid < a.b4) { W = a.W3; T = a.T3; K = a.K3; Nn = a.N3; t = bid - a.b3; }
    else                 { W = a.W4; T = a.T4; K = a.K4; Nn = a.N4; t = bid - a.b4; }
    int tilesx = Nn >> 5;
    int nb = (t % tilesx) * 32, kb = (t / tilesx) * 32;
    __shared__ float tt[32][33];
    int tx = threadIdx.x & 31, ty = threadIdx.x >> 5;
#pragma unroll
    for (int r = 0; r < 32; r += 8)
        tt[ty + r][tx] = W[(size_t)(kb + ty + r) * Nn + nb + tx];
    __syncthreads();
#pragma unroll
    for (int r = 0; r < 32; r += 8)
        T[(size_t)(nb + ty + r) * K + kb + tx] = __float2half(tt[tx][ty + r]);
}

// ---------------- MFMA GEMM: C[M][N] = A[M][K] @ Bt[N][K]^T, all fp16 in, fp16 out ----
// 128x128 tile, BK=64, 4 waves (2x2 of 64x64), global_load_lds staging with
// XOR-swizzled global source + linear LDS dest; swizzled ds_read_b128 fragment reads.
// T1: bijective XCD-aware block swizzle (m204).
__global__ __launch_bounds__(256) void gemm_mfma_kernel(const __half* __restrict__ A,
                                                        const __half* __restrict__ Bt,
                                                        __half* __restrict__ C,
                                                        int M, int N, int K) {
    __shared__ __align__(16) __half Asm[128 * 64];
    __shared__ __align__(16) __half Bsm[128 * 64];
    const int tid  = threadIdx.x;
    const int lane = tid & 63;
    const int wave = tid >> 6;

    // XCD swizzle (bijective for any nwg)
    const int nwg = (int)(gridDim.x * gridDim.y);
    const int lin = (int)(blockIdx.y * gridDim.x + blockIdx.x);
    const int q = nwg >> 3, r = nwg & 7;
    const int xcd = lin & 7, idx = lin >> 3;
    const int nid = (xcd < r ? xcd * (q + 1) : r * (q + 1) + (xcd - r) * q) + idx;
    const int bx = nid % (int)gridDim.x;
    const int by = nid / (int)gridDim.x;
    const int row0 = by * 128;
    const int col0 = bx * 128;

    const int l15 = lane & 15;
    const int l4  = lane >> 4;            // 0..3
    const int wm  = (wave >> 1) * 64;     // wave's m offset in tile
    const int wn  = (wave & 1) * 64;      // wave's n offset in tile

    const int sl_row = lane >> 3;              // 0..7
    const int sl_kch = (lane & 7) ^ sl_row;    // logical k-chunk to fetch (XOR involution)

    float4_t acc[4][4];
#pragma unroll
    for (int i = 0; i < 4; ++i)
#pragma unroll
        for (int j = 0; j < 4; ++j)
            acc[i][j] = (float4_t){0.f, 0.f, 0.f, 0.f};

    for (int k0 = 0; k0 < K; k0 += 64) {
#pragma unroll
        for (int i = 0; i < 4; ++i) {
            int rr = (i * 4 + wave) * 8 + sl_row;     // 0..127
            int ar = row0 + rr; if (ar >= M) ar = M - 1;   // clamp (values unused)
            const __half* ga = A + (size_t)ar * K + k0 + sl_kch * 8;
            char* la = (char*)Asm + ((i * 4 + wave) * 1024 + lane * 16);
            __builtin_amdgcn_global_load_lds((g_void*)ga, (l_void*)la, 16, 0, 0);
            const __half* gb = Bt + (size_t)(col0 + rr) * K + k0 + sl_kch * 8;
            char* lb = (char*)Bsm + ((i * 4 + wave) * 1024 + lane * 16);
            __builtin_amdgcn_global_load_lds((g_void*)gb, (l_void*)lb, 16, 0, 0);
        }
        __syncthreads();
#pragma unroll
        for (int kh = 0; kh < 2; ++kh) {
            half8_t af[4], bf[4];
#pragma unroll
            for (int f = 0; f < 4; ++f) {
                int rowa = wm + f * 16 + l15;
                int ca = (kh * 4 + l4) ^ (rowa & 7);
                af[f] = *(const half8_t*)((const char*)Asm + rowa * 128 + ca * 16);
                int rowb = wn + f * 16 + l15;
                int cb = (kh * 4 + l4) ^ (rowb & 7);
                bf[f] = *(const half8_t*)((const char*)Bsm + rowb * 128 + cb * 16);
            }
#pragma unroll
            for (int fm = 0; fm < 4; ++fm)
#pragma unroll
                for (int fn = 0; fn < 4; ++fn)
                    acc[fm][fn] = __builtin_amdgcn_mfma_f32_16x16x32_f16(af[fm], bf[fn], acc[fm][fn], 0, 0, 0);
        }
        __syncthreads();
    }

    // epilogue: C/D map col=lane&15, row=(lane>>4)*4+reg  [m89]
#pragma unroll
    for (int fm = 0; fm < 4; ++fm) {
#pragma unroll
        for (int r2 = 0; r2 < 4; ++r2) {
            int row = row0 + wm + fm * 16 + l4 * 4 + r2;
            if (row < M) {
#pragma unroll
                for (int fn = 0; fn < 4; ++fn) {
                    int col = col0 + wn + fn * 16 + l15;
                    C[(size_t)row * N + col] = __float2half(acc[fm][fn][r2]);
                }
            }
        }
    }
}

// ---------------- VALU GEMM (fallback path): C[M,N] = A[M,K] @ B[K,N] ----------------
template <typename TA, typename TC>
__global__ __launch_bounds__(256) void gemm_kernel(const TA* __restrict__ A,
                                                   const float* __restrict__ B,
                                                   TC* __restrict__ C,
                                                   int M, int N, int K) {
    __shared__ float As[16][64];
    __shared__ float Bs[16][64];
    const int tid  = threadIdx.x;
    const int row0 = blockIdx.y * 64, col0 = blockIdx.x * 64;
    const int am = tid >> 2, ak = (tid & 3) << 2;
    const int bk = tid >> 4, bn = (tid & 15) << 2;
    const int ty = (tid >> 4) << 2, tx = (tid & 15) << 2;
    float acc[4][4] = {};
    const int arow = row0 + am;
    for (int k0 = 0; k0 < K; k0 += 16) {
        float4 a4 = make_float4(0.f, 0.f, 0.f, 0.f);
        if (arow < M) a4 = ld4(A + (size_t)arow * K + k0 + ak);
        As[ak + 0][am] = a4.x; As[ak + 1][am] = a4.y;
        As[ak + 2][am] = a4.z; As[ak + 3][am] = a4.w;
        *(float4*)&Bs[bk][bn] = *(const float4*)(B + (size_t)(k0 + bk) * N + col0 + bn);
        __syncthreads();
#pragma unroll
        for (int k = 0; k < 16; ++k) {
            float4 ar = *(const float4*)&As[k][ty];
            float4 br = *(const float4*)&Bs[k][tx];
            acc[0][0] += ar.x * br.x; acc[0][1] += ar.x * br.y; acc[0][2] += ar.x * br.z; acc[0][3] += ar.x * br.w;
            acc[1][0] += ar.y * br.x; acc[1][1] += ar.y * br.y; acc[1][2] += ar.y * br.z; acc[1][3] += ar.y * br.w;
            acc[2][0] += ar.z * br.x; acc[2][1] += ar.z * br.y; acc[2][2] += ar.z * br.z; acc[2][3] += ar.z * br.w;
            acc[3][0] += ar.w * br.x; acc[3][1] += ar.w * br.y; acc[3][2] += ar.w * br.z; acc[3][3] += ar.w * br.w;
        }
        __syncthreads();
    }
#pragma unroll
    for (int i = 0; i < 4; ++i) {
        int r = row0 + ty + i;
        if (r < M) {
            float4 o = make_float4(acc[i][0], acc[i][1], acc[i][2], acc[i][3]);
            st4(C + (size_t)r * N + col0 + tx, o);
        }
    }
}

// ---------------- attention logits, vectorized (fp16 ht) ----------------
template <int C>
__global__ void al_vec_kernel(const __half* __restrict__ ht, const float* __restrict__ a_src,
                              const float* __restrict__ a_dst, float* __restrict__ al_s,
                              float* __restrict__ al_d, int N) {
    int wid  = (int)((blockIdx.x * blockDim.x + threadIdx.x) >> 6);
    int lane = threadIdx.x & 63;
    if (wid >= N * NHEADS) return;
    int n = wid / NHEADS, h = wid % NHEADS;
    float ss = 0.f, sd = 0.f;
    int c0 = lane * 4;
    if (c0 < C) {
        const __half* hp = ht + (size_t)n * (NHEADS * C) + h * C + c0;
        half4_t v = *(const half4_t*)hp;
        float4 as4 = *(const float4*)(a_src + h * C + c0);
        float4 ad4 = *(const float4*)(a_dst + h * C + c0);
        float v0 = (float)v[0], v1 = (float)v[1], v2 = (float)v[2], v3 = (float)v[3];
        ss = v0 * as4.x + v1 * as4.y + v2 * as4.z + v3 * as4.w;
        sd = v0 * ad4.x + v1 * ad4.y + v2 * ad4.z + v3 * ad4.w;
    }
#pragma unroll
    for (int off = 32; off > 0; off >>= 1) {
        ss += __shfl_down(ss, off);
        sd += __shfl_down(sd, off);
    }
    if (lane == 0) { al_s[wid] = ss; al_d[wid] = sd; }
}

// ---------------- segment softmax: one WAVE per node ----------------
// lane = head + 8*edge_slot. alpha stored UNNORMALIZED; inv_d applied in agg.
__global__ __launch_bounds__(256) void alpha_wave_kernel(const int* __restrict__ offsets,
                                                         const int* __restrict__ perm_src,
                                                         const float* __restrict__ al_s,
                                                         const float* __restrict__ al_d,
                                                         float* __restrict__ alpha,
                                                         float* __restrict__ inv_d, int N) {
    int wid  = (int)((blockIdx.x * blockDim.x + threadIdx.x) >> 6);
    int lane = threadIdx.x & 63;
    if (wid >= N) return;
    int n = wid;
    int h = lane & 7, es = lane >> 3;   // 8 heads x 8 edge slots
    int s = offsets[n], e = offsets[n + 1];
    float ad = al_d[(size_t)n * 8 + h];
    float m = -1e30f;
    for (int p0 = s; p0 < e; p0 += 8) {
        int p = p0 + es;
        if (p < e) {
            int src = perm_src[p];
            m = fmaxf(m, lrelu_f(al_s[(size_t)src * 8 + h] + ad));
        }
    }
#pragma unroll
    for (int off = 8; off < 64; off <<= 1) m = fmaxf(m, __shfl_xor(m, off));
    float den = 0.f;
    for (int p0 = s; p0 < e; p0 += 8) {
        int p = p0 + es;
        if (p < e) {
            int src = perm_src[p];
            float ex = expf(lrelu_f(al_s[(size_t)src * 8 + h] + ad) - m);
            alpha[(size_t)p * 8 + h] = ex;
            den += ex;
        }
    }
#pragma unroll
    for (int off = 8; off < 64; off <<= 1) den += __shfl_xor(den, off);
    if (es == 0) inv_d[(size_t)n * 8 + h] = 1.f / (den + 1e-16f);
}

// ---------------- aggregation, vectorized + 4-deep MLP pipeline ----------------
// MODE 0: out[n,j] = elu(inv[head(j)] * acc[j] + bias[j])      (__half out)
// MODE 1: out[n,c] = elu(mean_h inv[h]*acc[h*C+c] + bias[c])   (float out)
template <int HC, int C, int MODE>
__global__ __launch_bounds__(256) void agg_vec_kernel(const __half* __restrict__ ht,
                                                      const float* __restrict__ alpha,
                                                      const float* __restrict__ inv_d,
                                                      const int* __restrict__ offsets,
                                                      const int* __restrict__ perm_src,
                                                      const float* __restrict__ bias,
                                                      void* __restrict__ outv, int N) {
    constexpr int V = HC / 256;          // 2 (HC=512) or 8 (HC=2048)
    int n = blockIdx.x;
    int tid = threadIdx.x;
    const int head = (tid * V) / C;      // constant per thread
    float acc[V];
#pragma unroll
    for (int i = 0; i < V; ++i) acc[i] = 0.f;
    int s = offsets[n], e = offsets[n + 1];
    const __half* base = ht + (size_t)tid * V;
    const float* ap = alpha + head;
    int p = s;
    for (; p + 4 <= e; p += 4) {
        int s0 = perm_src[p], s1 = perm_src[p + 1], s2 = perm_src[p + 2], s3 = perm_src[p + 3];
        float a0 = ap[(size_t)p * 8],       a1 = ap[(size_t)(p + 1) * 8];
        float a2 = ap[(size_t)(p + 2) * 8], a3 = ap[(size_t)(p + 3) * 8];
        if (V == 8) {
            half8_t v0 = *(const half8_t*)(base + (size_t)s0 * HC);
            half8_t v1 = *(const half8_t*)(base + (size_t)s1 * HC);
            half8_t v2 = *(const half8_t*)(base + (size_t)s2 * HC);
            half8_t v3 = *(const half8_t*)(base + (size_t)s3 * HC);
#pragma unroll
            for (int i = 0; i < 8; ++i) acc[i] += a0 * (float)v0[i];
#pragma unroll
            for (int i = 0; i < 8; ++i) acc[i] += a1 * (float)v1[i];
#pragma unroll
            for (int i = 0; i < 8; ++i) acc[i] += a2 * (float)v2[i];
#pragma unroll
            for (int i = 0; i < 8; ++i) acc[i] += a3 * (float)v3[i];
        } else {
            __half2 w0 = *(const __half2*)(base + (size_t)s0 * HC);
            __half2 w1 = *(const __half2*)(base + (size_t)s1 * HC);
            __half2 w2 = *(const __half2*)(base + (size_t)s2 * HC);
            __half2 w3 = *(const __half2*)(base + (size_t)s3 * HC);
            acc[0] += a0 * __half2float(w0.x); acc[1] += a0 * __half2float(w0.y);
            acc[0] += a1 * __half2float(w1.x); acc[1] += a1 * __half2float(w1.y);
            acc[0] += a2 * __half2float(w2.x); acc[1] += a2 * __half2float(w2.y);
            acc[0] += a3 * __half2float(w3.x); acc[1] += a3 * __half2float(w3.y);
        }
    }
    for (; p < e; ++p) {
        int src = perm_src[p];
        float a = ap[(size_t)p * 8];
        const __half* hp = base + (size_t)src * HC;
        if (V == 8) {
            half8_t v = *(const half8_t*)hp;
#pragma unroll
            for (int i = 0; i < 8; ++i) acc[i] += a * (float)v[i];
        } else {
            __half2 v2 = *(const __half2*)hp;
            acc[0] += a * __half2float(v2.x);
            acc[1] += a * __half2float(v2.y);
        }
    }
    float inv = inv_d[(size_t)n * NHEADS + head];
    if (MODE == 0) {
        __half* out = (__half*)outv;
        if (V == 8) {
            half8_t o;
#pragma unroll
            for (int i = 0; i < 8; ++i)
                o[i] = (_Float16)elu_f(acc[i] * inv + bias[tid * 8 + i]);
            *(half8_t*)(out + (size_t)n * HC + tid * 8) = o;
        } else {
            __half2 o;
            o.x = __float2half(elu_f(acc[0] * inv + bias[tid * 2 + 0]));
            o.y = __float2half(elu_f(acc[1] * inv + bias[tid * 2 + 1]));
            *(__half2*)(out + (size_t)n * HC + tid * 2) = o;
        }
    } else {
        // V==8, C=256: LDS transpose-reduce over heads
        __shared__ float sm[256][8];
#pragma unroll
        for (int i = 0; i < 8; ++i) sm[tid][i] = acc[i] * inv;
        __syncthreads();
        float ssum = 0.f;
#pragma unroll
        for (int h = 0; h < 8; ++h) ssum += sm[h * 32 + (tid >> 3)][tid & 7];
        float* out = (float*)outv;
        out[(size_t)n * C + tid] = elu_f(ssum * (1.f / NHEADS) + bias[tid]);
    }
}

// ---------------- fallback scalar kernels (paths 0-2) ----------------
template <typename TH>
__global__ void al_kernel(const TH* __restrict__ ht, const float* __restrict__ a_src,
                          const float* __restrict__ a_dst, float* __restrict__ al_s,
                          float* __restrict__ al_d, int N, int C) {
    int wid  = (int)((blockIdx.x * blockDim.x + threadIdx.x) >> 6);
    int lane = threadIdx.x & 63;
    if (wid >= N * NHEADS) return;
    int n = wid / NHEADS, h = wid % NHEADS;
    const TH* hp = ht + (size_t)n * (NHEADS * C) + h * C;
    float ss = 0.f, sd = 0.f;
    for (int c = lane; c < C; c += 64) {
        float v = scl(hp[c]);
        ss += v * a_src[h * C + c];
        sd += v * a_dst[h * C + c];
    }
#pragma unroll
    for (int off = 32; off > 0; off >>= 1) {
        ss += __shfl_down(ss, off);
        sd += __shfl_down(sd, off);
    }
    if (lane == 0) { al_s[wid] = ss; al_d[wid] = sd; }
}

__global__ void alpha_kernel(const int* __restrict__ offsets, const int* __restrict__ perm_src,
                             const float* __restrict__ al_s, const float* __restrict__ al_d,
                             float* __restrict__ alpha, int N) {
    int idx = blockIdx.x * blockDim.x + threadIdx.x;
    if (idx >= N * NHEADS) return;
    int n = idx / NHEADS, h = idx % NHEADS;
    int s = offsets[n], e = offsets[n + 1];
    float ad = al_d[idx];
    float m = -1e30f;
    for (int p = s; p < e; ++p) {
        float v = lrelu_f(al_s[perm_src[p] * NHEADS + h] + ad);
        m = fmaxf(m, v);
    }
    float denom = 0.f;
    for (int p = s; p < e; ++p) {
        float v  = lrelu_f(al_s[perm_src[p] * NHEADS + h] + ad);
        float ex = expf(v - m);
        alpha[(size_t)p * NHEADS + h] = ex;
        denom += ex;
    }
    float inv = 1.f / (denom + 1e-16f);
    for (int p = s; p < e; ++p) alpha[(size_t)p * NHEADS + h] *= inv;
}

template <int HC, int C, int MODE, typename TH, typename TO>
__global__ __launch_bounds__(256) void agg_kernel(const TH* __restrict__ ht,
                                                  const float* __restrict__ alpha,
                                                  const int* __restrict__ offsets,
                                                  const int* __restrict__ perm_src,
                                                  const float* __restrict__ bias,
                                                  TO* __restrict__ out, int N) {
    constexpr int PER = HC / 256;
    int n = blockIdx.x;
    int tid = threadIdx.x;
    float acc[PER];
#pragma unroll
    for (int i = 0; i < PER; ++i) acc[i] = 0.f;
    int s = offsets[n], e = offsets[n + 1];
    for (int p = s; p < e; ++p) {
        int src = perm_src[p];
        const TH* hp = ht + (size_t)src * HC;
#pragma unroll
        for (int i = 0; i < PER; ++i) {
            int j = tid + i * 256;
            float a = alpha[(size_t)p * NHEADS + (j / C)];
            acc[i] += a * scl(hp[j]);
        }
    }
    if (MODE == 0) {
#pragma unroll
        for (int i = 0; i < PER; ++i) {
            int j = tid + i * 256;
            sst(&out[(size_t)n * HC + j], elu_f(acc[i] + bias[j]));
        }
    } else {
        float srow = 0.f;
#pragma unroll
        for (int i = 0; i < PER; ++i) srow += acc[i];
        sst(&out[(size_t)n * C + tid], elu_f(srow * (1.f / NHEADS) + bias[tid]));
    }
}

// ---------------- pooling (fallback path kernels) ----------------
__global__ void gstart_kernel(const int* __restrict__ batch, int* __restrict__ gstart, int N) {
    int n = blockIdx.x * blockDim.x + threadIdx.x;
    if (n > N) return;
    if (n == 0) {
        int b0 = batch[0];
        for (int g = 0; g <= b0; ++g) gstart[g] = 0;
    } else if (n == N) {
        int bl = batch[N - 1];
        for (int g = bl + 1; g <= NG; ++g) gstart[g] = N;
    } else {
        int bp = batch[n - 1], bc = batch[n];
        for (int g = bp + 1; g <= bc; ++g) gstart[g] = n;
    }
}

__global__ void pool_kernel(const float* __restrict__ h5, const int* __restrict__ gstart,
                            float* __restrict__ pooled) {
    int g = blockIdx.x, c = threadIdx.x;  // 256 threads
    int s = gstart[g], e = gstart[g + 1];
    float sum = 0.f;
    for (int n = s; n < e; ++n) sum += h5[(size_t)n * 256 + c];
    float cnt = fmaxf((float)(e - s), 1.f);
    pooled[g * 256 + c] = elu_f(sum / cnt);
}

__global__ void linear_kernel(const float* __restrict__ pooled, const float* __restrict__ W,
                              const float* __restrict__ b, float* __restrict__ out) {
    int g = blockIdx.x, c = threadIdx.x;  // 128 threads
    float s = b[c];
    for (int k = 0; k < 256; ++k) s += pooled[g * 256 + k] * W[k * 128 + c];
    out[g * 128 + c] = s;
}

// ---------------- fused pool + linear (path 3) ----------------
__device__ __forceinline__ int lb_dev(const int* a, int n, int key) {
    int lo = 0, hi = n;
    while (lo < hi) { int mid = (lo + hi) >> 1; if (a[mid] < key) lo = mid + 1; else hi = mid; }
    return lo;
}

__global__ __launch_bounds__(256) void pool_linear_kernel(const float* __restrict__ h5,
                                                          const int* __restrict__ batch, int N,
                                                          const float* __restrict__ Wlin,
                                                          const float* __restrict__ blin,
                                                          float* __restrict__ out) {
    int g = blockIdx.x, c = threadIdx.x;
    int s = lb_dev(batch, N, g);
    int e = lb_dev(batch, N, g + 1);
    __shared__ float pooled_s[256];
    float sum = 0.f;
    for (int n = s; n < e; ++n) sum += h5[(size_t)n * 256 + c];
    float cnt = fmaxf((float)(e - s), 1.f);
    pooled_s[c] = elu_f(sum / cnt);
    __syncthreads();
    if (c < 128) {
        float acc = blin[c];
        for (int k = 0; k < 256; ++k) acc += pooled_s[k] * Wlin[k * 128 + c];
        out[g * 128 + c] = acc;
    }
}

// ---------------- fallback pipeline (VALU GEMM, typed) ----------------
template <typename TIO, typename TH>
static void run_pipeline(const float* x, const float* const* W, const float* const* asrc,
                         const float* const* adst, const float* const* bias,
                         char* rawIO, char* rawHT,
                         float* al_s, float* al_d, float* alpha_buf,
                         const int* offsets, const int* perm_src,
                         int N, hipStream_t stream) {
    TIO* bufIO = (TIO*)rawIO;
    TH*  bufHT = (TH*)rawHT;
    {
        dim3 g(512 / 64, (N + 63) / 64);
        gemm_kernel<float, TH><<<g, 256, 0, stream>>>(x, W[0], bufHT, N, 512, 128);
        al_kernel<TH><<<(N * NHEADS * 64 + 255) / 256, 256, 0, stream>>>(bufHT, asrc[0], adst[0], al_s, al_d, N, 64);
        alpha_kernel<<<(N * NHEADS + 255) / 256, 256, 0, stream>>>(offsets, perm_src, al_s, al_d, alpha_buf, N);
        agg_kernel<512, 64, 0, TH, TIO><<<N, 256, 0, stream>>>(bufHT, alpha_buf, offsets, perm_src, bias[0], bufIO, N);
    }
    int Kdim = 512;
    for (int l = 1; l < 5; ++l) {
        dim3 g(2048 / 64, (N + 63) / 64);
        gemm_kernel<TIO, TH><<<g, 256, 0, stream>>>(bufIO, W[l], bufHT, N, 2048, Kdim);
        al_kernel<TH><<<(N * NHEADS * 64 + 255) / 256, 256, 0, stream>>>(bufHT, asrc[l], adst[l], al_s, al_d, N, 256);
        alpha_kernel<<<(N * NHEADS + 255) / 256, 256, 0, stream>>>(offsets, perm_src, al_s, al_d, alpha_buf, N);
        if (l < 4)
            agg_kernel<2048, 256, 0, TH, TIO><<<N, 256, 0, stream>>>(bufHT, alpha_buf, offsets, perm_src, bias[l], bufIO, N);
        else
            agg_kernel<2048, 256, 1, TH, float><<<N, 256, 0, stream>>>(bufHT, alpha_buf, offsets, perm_src, bias[l], (float*)rawIO, N);
        Kdim = 2048;
    }
}

// ---------------- host ----------------
extern "C" void kernel_launch(void* const* d_in, const int* in_sizes, int n_in,
                              void* d_out, int out_size, void* d_ws, size_t ws_size,
                              hipStream_t stream) {
    const float* x     = (const float*)d_in[0];
    const int*   ei    = (const int*)d_in[1];
    const int*   batch = (const int*)d_in[2];
    const float* W[5]    = {(const float*)d_in[3],  (const float*)d_in[7],  (const float*)d_in[11],
                            (const float*)d_in[15], (const float*)d_in[19]};
    const float* asrc[5] = {(const float*)d_in[4],  (const float*)d_in[8],  (const float*)d_in[12],
                            (const float*)d_in[16], (const float*)d_in[20]};
    const float* adst[5] = {(const float*)d_in[5],  (const float*)d_in[9],  (const float*)d_in[13],
                            (const float*)d_in[17], (const float*)d_in[21]};
    const float* bias[5] = {(const float*)d_in[6],  (const float*)d_in[10], (const float*)d_in[14],
                            (const float*)d_in[18], (const float*)d_in[22]};
    const float* Wlin = (const float*)d_in[23];
    const float* blin = (const float*)d_in[24];

    const int N    = in_sizes[0] / 128;
    const int E    = in_sizes[1] / 2;
    const int Etot = E + N;

    auto align256 = [](size_t b) { return (b + 255) & ~(size_t)255; };

    size_t sz_counts = align256((size_t)N * 4);
    size_t sz_off    = align256((size_t)(N + 1) * 4);
    size_t sz_cur    = align256((size_t)N * 4);
    size_t sz_perm   = align256((size_t)Etot * 4);
    size_t sz_al     = align256((size_t)N * NHEADS * 4);
    size_t sz_alpha  = align256((size_t)Etot * NHEADS * 4);
    size_t sz_inv    = align256((size_t)N * NHEADS * 4);
    size_t sz_gst    = align256((size_t)(NG + 1) * 4);
    size_t sz_pool   = align256((size_t)NG * 256 * 4);
    size_t misc = sz_counts + sz_off + sz_cur + sz_perm + 2 * sz_al + sz_alpha + sz_inv + sz_gst + sz_pool;

    size_t bigf  = align256((size_t)N * 2048 * sizeof(float));
    size_t bigh  = align256((size_t)N * 2048 * sizeof(__half));
    // per-layer transposed weights (all resident simultaneously)
    const int Kd[5] = {128, 512, 2048, 2048, 2048};
    const int Nd[5] = {512, 2048, 2048, 2048, 2048};
    size_t sz_wt_each[5], sz_wt_all = 0;
    for (int l = 0; l < 5; ++l) { sz_wt_each[l] = align256((size_t)Kd[l] * Nd[l] * sizeof(__half)); sz_wt_all += sz_wt_each[l]; }
    size_t sz_x16 = align256((size_t)N * 128 * sizeof(__half));

    int path;
    if      (ws_size >= misc + 2 * bigh + sz_wt_all + sz_x16) path = 3;  // MFMA fp16 pipeline
    else if (ws_size >= misc + 2 * bigf)                      path = 0;
    else if (ws_size >= misc + bigf + bigh)                   path = 1;
    else if (ws_size >= misc + 2 * bigh)                      path = 2;
    else {
        hipMemsetAsync(d_out, 0, (size_t)out_size * sizeof(float), stream);
        return;
    }

    char* ws = (char*)d_ws;
    size_t off = 0;
    auto carve = [&](size_t bytes) { void* p = ws + off; off += bytes; return p; };
    int*   counts   = (int*)carve(sz_counts);
    int*   offsets  = (int*)carve(sz_off);
    int*   cursor   = (int*)carve(sz_cur);
    int*   perm_src = (int*)carve(sz_perm);
    float* al_s     = (float*)carve(sz_al);
    float* al_d     = (float*)carve(sz_al);
    float* alpha    = (float*)carve(sz_alpha);
    float* inv_d    = (float*)carve(sz_inv);
    int*   gstart   = (int*)carve(sz_gst);
    float* pooled   = (float*)carve(sz_pool);

    // CSR build
    hipMemsetAsync(counts, 0, (size_t)N * 4, stream);
    hist_kernel<<<(Etot + 255) / 256, 256, 0, stream>>>(ei, E, Etot, counts);
    scan_kernel<<<1, 256, 0, stream>>>(counts, offsets, cursor, N);
    scatter_kernel<<<(Etot + 255) / 256, 256, 0, stream>>>(ei, E, Etot, cursor, perm_src);

    if (path == 3) {
        char*   rawIO = (char*)carve(bigh);
        char*   rawHT = (char*)carve(bigh);
        __half* Wt[5];
        for (int l = 0; l < 5; ++l) Wt[l] = (__half*)carve(sz_wt_each[l]);
        __half* x16   = (__half*)carve(sz_x16);
        __half* bufIO = (__half*)rawIO;
        __half* bufHT = (__half*)rawHT;

        // fused prep: x->fp16 + all 5 weight transposes
        PrepArgs pa;
        pa.x = x; pa.x16 = x16; pa.n4 = (long)N * 128 / 4;
        pa.W0 = W[0]; pa.W1 = W[1]; pa.W2 = W[2]; pa.W3 = W[3]; pa.W4 = W[4];
        pa.T0 = Wt[0]; pa.T1 = Wt[1]; pa.T2 = Wt[2]; pa.T3 = Wt[3]; pa.T4 = Wt[4];
        pa.K0 = Kd[0]; pa.K1 = Kd[1]; pa.K2 = Kd[2]; pa.K3 = Kd[3]; pa.K4 = Kd[4];
        pa.N0 = Nd[0]; pa.N1 = Nd[1]; pa.N2 = Nd[2]; pa.N3 = Nd[3]; pa.N4 = Nd[4];
        int bacc = (int)((pa.n4 + 255) / 256);
        pa.b0 = bacc;
        int bends[5];
        for (int l = 0; l < 5; ++l) { bacc += (Nd[l] / 32) * (Kd[l] / 32); bends[l] = bacc; }
        pa.b1 = bends[0]; pa.b2 = bends[1]; pa.b3 = bends[2]; pa.b4 = bends[3]; pa.b5 = bends[4];
        prep_kernel<<<pa.b5, 256, 0, stream>>>(pa);

        const __half* curA = x16;
        int Kdim = 128;
        for (int l = 0; l < 5; ++l) {
            const int C  = (l == 0) ? 64 : 256;
            const int HC = NHEADS * C;
            {
                dim3 gg(HC / 128, (N + 127) / 128);
                gemm_mfma_kernel<<<gg, 256, 0, stream>>>(curA, Wt[l], bufHT, N, HC, Kdim);
            }
            if (l == 0)
                al_vec_kernel<64><<<(N * NHEADS * 64 + 255) / 256, 256, 0, stream>>>(bufHT, asrc[l], adst[l], al_s, al_d, N);
            else
                al_vec_kernel<256><<<(N * NHEADS * 64 + 255) / 256, 256, 0, stream>>>(bufHT, asrc[l], adst[l], al_s, al_d, N);
            alpha_wave_kernel<<<(N * 64 + 255) / 256, 256, 0, stream>>>(offsets, perm_src, al_s, al_d, alpha, inv_d, N);
            if (l == 0)
                agg_vec_kernel<512, 64, 0><<<N, 256, 0, stream>>>(bufHT, alpha, inv_d, offsets, perm_src, bias[l], bufIO, N);
            else if (l < 4)
                agg_vec_kernel<2048, 256, 0><<<N, 256, 0, stream>>>(bufHT, alpha, inv_d, offsets, perm_src, bias[l], bufIO, N);
            else
                agg_vec_kernel<2048, 256, 1><<<N, 256, 0, stream>>>(bufHT, alpha, inv_d, offsets, perm_src, bias[l], (float*)rawIO, N);
            curA = bufIO;
            Kdim = (l == 0) ? 512 : 2048;
        }
        pool_linear_kernel<<<NG, 256, 0, stream>>>((const float*)rawIO, batch, N, Wlin, blin, (float*)d_out);
        return;
    }

    char* rawIO = (char*)carve(path == 2 ? bigh : bigf);
    char* rawHT = (char*)carve(path == 0 ? bigf : bigh);

    if (path == 0)
        run_pipeline<float, float>(x, W, asrc, adst, bias, rawIO, rawHT, al_s, al_d, alpha, offsets, perm_src, N, stream);
    else if (path == 1)
        run_pipeline<float, __half>(x, W, asrc, adst, bias, rawIO, rawHT, al_s, al_d, alpha, offsets, perm_src, N, stream);
    else
        run_pipeline<__half, __half>(x, W, asrc, adst, bias, rawIO, rawHT, al_s, al_d, alpha, offsets, perm_src, N, stream);

    gstart_kernel<<<(N + 1 + 255) / 256, 256, 0, stream>>>(batch, gstart, N);
    pool_kernel<<<NG, 256, 0, stream>>>((const float*)rawIO, gstart, pooled);
    linear_kernel<<<NG, 128, 0, stream>>>(pooled, Wlin, blin, (float*)d_out);
}